// Round 4
// baseline (1252.416 us; speedup 1.0000x reference)
//
#include <hip/hip_runtime.h>
#include <stdint.h>

// ---------------------------------------------------------------------------
// ActorCriticRNN on MI355X.
//   prep:  weights -> bf16 (B^T layout), Wh -> MFMA-fragment-linear.
//   G12:   FUSED, barrier-free: A and B fragments loaded DIRECT from global
//          (A row-major -> 8 consecutive k per lane; B L2-resident weights).
//          Only the emb transpose (acc -> A-frag) goes through LDS (1 barrier).
//          gi written in GRU-packed gate-plane layout.
//   GRU:   chunk-parallel speculation (dones p=0.5 reset h). Main: 256 WGs.
//          gi prefetched one step ahead; y staged in LDS, 16B/lane stores.
//          Fixup parallel over 240 (chunk,tile) WGs + sequential fallback
//          guarded by a flag (prob ~2^-32 per row-chunk).
//   G3:    k_gemm_ac: ZERO-LDS zero-barrier GEMM, frags direct from global.
//   G4:    k_logits: ZERO-LDS zero-barrier; masked by avail.
//   G5:    critic dot; out0: hidden = y[T-1].
// ---------------------------------------------------------------------------

typedef short short8 __attribute__((ext_vector_type(8)));
typedef float f32x4  __attribute__((ext_vector_type(4)));

#define T_DIM 512
#define CHUNK 32
#define NCH   16
#define GIPL  ((size_t)33554432)   // gi gate-plane size in shorts (8192*512*8)

// output offsets (fp32 elements)
#define OUT_HID  ((size_t)0)
#define OUT_LC1  ((size_t)65536)
#define OUT_LC2  ((size_t)4259840)
#define OUT_MC   ((size_t)8454144)
#define OUT_HINT ((size_t)10551296)
#define OUT_CRIT ((size_t)18939904)

__device__ __forceinline__ unsigned short f2bf(float f) {
    unsigned u = __float_as_uint(f);
    u += 0x7fffu + ((u >> 16) & 1u);          // round-to-nearest-even
    return (unsigned short)(u >> 16);
}
__device__ __forceinline__ float bf2f(unsigned short h) {
    return __uint_as_float(((unsigned)h) << 16);
}

__device__ __forceinline__ unsigned short gru_cell(
    float ir, float iz, float inn, float ho,
    float hrv, float hzv, float hnv, float bh)
{
    float rg = 1.f / (1.f + __expf(-(ir + hrv)));
    float z  = 1.f / (1.f + __expf(-(iz + hzv)));
    float ex = __expf(2.f * (inn + rg * (hnv + bh)));
    float n  = 1.f - 2.f / (ex + 1.f);        // tanh, inf-safe
    return f2bf((1.f - z) * n + z * ho);
}

// ---------------------------------------------------------------------------
// prep (verified; + zero the fixup-fallback flag)
// ---------------------------------------------------------------------------
__global__ __launch_bounds__(256, 4) void k_prep(
    const float* __restrict__ W_emb, const float* __restrict__ Wi,
    const float* __restrict__ Wh,    const float* __restrict__ W_a,
    const float* __restrict__ W_c1,  const float* __restrict__ W_lc1,
    const float* __restrict__ W_lc2, const float* __restrict__ W_mc,
    const float* __restrict__ W_hint,
    const float* __restrict__ b_lc1, const float* __restrict__ b_lc2,
    const float* __restrict__ b_mc,  const float* __restrict__ b_hint,
    unsigned short* __restrict__ WembT, unsigned short* __restrict__ WiT,
    unsigned short* __restrict__ WhF,   unsigned short* __restrict__ WacT,
    unsigned short* __restrict__ WlogT, float* __restrict__ blog,
    int* __restrict__ fixflag)
{
    int i = blockIdx.x * 256 + threadIdx.x;
    if (i < 131072) {                         // WembT[n][k] = W_emb[k][n]
        int n = i >> 9, k = i & 511;
        WembT[i] = f2bf(W_emb[k * 256 + n]);
        return;
    }
    i -= 131072;
    if (i < 196608) {                         // WiT[n][k] = Wi[k][n]
        int n = i >> 8, k = i & 255;
        WiT[i] = f2bf(Wi[k * 768 + n]);
        return;
    }
    i -= 196608;
    if (i < 196608) {                         // Wh fragment-linear
        int jj = i & 7, L = (i >> 3) & 63, ks = (i >> 9) & 7, rest = i >> 12;
        int w = rest / 6, i6 = rest % 6, rho = i6 >> 1, s = i6 & 1;
        int k   = ks * 32 + ((L >> 4) << 3) + jj;
        int col = rho * 256 + w * 32 + s * 16 + (L & 15);
        WhF[i] = f2bf(Wh[k * 768 + col]);
        return;
    }
    i -= 196608;
    if (i < 131072) {                         // WacT
        int n = i >> 8, k = i & 255;
        WacT[i] = f2bf(n < 256 ? W_a[k * 256 + n] : W_c1[k * 256 + (n - 256)]);
        return;
    }
    i -= 131072;
    if (i < 40960) {                          // WlogT (N padded to 160)
        int n = i >> 8, k = i & 255;
        float v;
        if      (n < 32)  v = W_lc1[k * 32 + n];
        else if (n < 64)  v = W_lc2[k * 32 + (n - 32)];
        else if (n < 80)  v = W_mc [k * 16 + (n - 64)];
        else if (n < 144) v = W_hint[k * 64 + (n - 80)];
        else              v = 0.f;
        WlogT[i] = f2bf(v);
        return;
    }
    i -= 40960;
    if (i < 160) {
        float v;
        if      (i < 32)  v = b_lc1[i];
        else if (i < 64)  v = b_lc2[i - 32];
        else if (i < 80)  v = b_mc [i - 64];
        else if (i < 144) v = b_hint[i - 80];
        else              v = 0.f;
        blog[i] = v;
        return;
    }
    i -= 160;
    if (i == 0) *fixflag = 0;
}

// ---------------------------------------------------------------------------
// FUSED G1+G2, barrier-free frag loads.
// 2048 blocks x 64 rows, 512 threads = 8 waves (2m x 4n).
//   phase 1: acc = obs @ WembT (K=512), A fp32->bf16 per-lane direct,
//            B direct from L2-hot WembT. relu+bias -> eS (LDS). 1 barrier.
//   phase 2: 3 gate-chunks: gi = eS @ WiT_chunk + bi, A-frags via ds_read
//            from eS, B direct. Packed epilogue (verified formulas).
// ---------------------------------------------------------------------------
__global__ __launch_bounds__(512, 4) void k_fused_g12(
    const float* __restrict__ obs, const unsigned short* __restrict__ WembT,
    const float* __restrict__ b_emb, const unsigned short* __restrict__ WiT,
    const float* __restrict__ bi, unsigned short* __restrict__ out)
{
    __shared__ unsigned short eS[64][264];
    const int tid = threadIdx.x, w = tid >> 6, L = tid & 63;
    const int mq = (w >> 2) * 32, nq = (w & 3) * 64;
    const int m0 = blockIdx.x * 64;
    const int lc = L & 15, g8 = (L >> 4) * 8, lr = (L >> 4) * 4;

    f32x4 acc[2][4];
#pragma unroll
    for (int i = 0; i < 2; i++)
#pragma unroll
        for (int j = 0; j < 4; j++) acc[i][j] = 0;

    // ---- phase 1: acc = obs @ WembT, direct frag loads ----
    const float* a0p = obs + (size_t)(m0 + mq + lc) * 512 + g8;
    const float* a1p = obs + (size_t)(m0 + mq + 16 + lc) * 512 + g8;
#pragma unroll 4
    for (int kk = 0; kk < 512; kk += 32) {
        short8 a[2], b[4];
        {
            f32x4 v0 = *(const f32x4*)(a0p + kk);
            f32x4 v1 = *(const f32x4*)(a0p + kk + 4);
            short8 pk;
            pk[0] = (short)f2bf(v0[0]); pk[1] = (short)f2bf(v0[1]);
            pk[2] = (short)f2bf(v0[2]); pk[3] = (short)f2bf(v0[3]);
            pk[4] = (short)f2bf(v1[0]); pk[5] = (short)f2bf(v1[1]);
            pk[6] = (short)f2bf(v1[2]); pk[7] = (short)f2bf(v1[3]);
            a[0] = pk;
        }
        {
            f32x4 v0 = *(const f32x4*)(a1p + kk);
            f32x4 v1 = *(const f32x4*)(a1p + kk + 4);
            short8 pk;
            pk[0] = (short)f2bf(v0[0]); pk[1] = (short)f2bf(v0[1]);
            pk[2] = (short)f2bf(v0[2]); pk[3] = (short)f2bf(v0[3]);
            pk[4] = (short)f2bf(v1[0]); pk[5] = (short)f2bf(v1[1]);
            pk[6] = (short)f2bf(v1[2]); pk[7] = (short)f2bf(v1[3]);
            a[1] = pk;
        }
#pragma unroll
        for (int j = 0; j < 4; j++)
            b[j] = *(const short8*)(WembT + (size_t)(nq + j * 16 + lc) * 512 + kk + g8);
#pragma unroll
        for (int i = 0; i < 2; i++)
#pragma unroll
            for (int j = 0; j < 4; j++)
                acc[i][j] = __builtin_amdgcn_mfma_f32_16x16x32_bf16(a[i], b[j], acc[i][j], 0, 0, 0);
    }
    // epilogue phase 1: relu -> bf16 -> eS
#pragma unroll
    for (int i = 0; i < 2; i++)
#pragma unroll
        for (int j = 0; j < 4; j++) {
            int col = nq + j * 16 + lc;
            float bv = b_emb[col];
#pragma unroll
            for (int rg = 0; rg < 4; rg++) {
                int row = mq + i * 16 + lr + rg;
                eS[row][col] = f2bf(fmaxf(acc[i][j][rg] + bv, 0.f));
            }
        }
    __syncthreads();

    // ---- phase 2: gi = eS @ WiT + bi, 3 gate chunks, no barriers ----
    for (int nc = 0; nc < 3; nc++) {
#pragma unroll
        for (int i = 0; i < 2; i++)
#pragma unroll
            for (int j = 0; j < 4; j++) acc[i][j] = 0;

#pragma unroll 2
        for (int kk = 0; kk < 256; kk += 32) {
            short8 a[2], b[4];
#pragma unroll
            for (int i = 0; i < 2; i++)
                a[i] = *(const short8*)&eS[mq + i * 16 + lc][kk + g8];
#pragma unroll
            for (int j = 0; j < 4; j++)
                b[j] = *(const short8*)(WiT + (size_t)(nc * 256 + nq + j * 16 + lc) * 256 + kk + g8);
#pragma unroll
            for (int i = 0; i < 2; i++)
#pragma unroll
                for (int j = 0; j < 4; j++)
                    acc[i][j] = __builtin_amdgcn_mfma_f32_16x16x32_bf16(a[i], b[j], acc[i][j], 0, 0, 0);
        }
        // packed epilogue (same verified formulas)
#pragma unroll
        for (int i = 0; i < 2; i++) {
            const int row0  = m0 + mq + i * 16 + lr;
            const int t     = row0 >> 8;
            const int g     = (row0 >> 4) & 15;
            const int rowg2 = (row0 >> 2) & 3;
#pragma unroll
            for (int jh = 0; jh < 2; jh++) {
                const int colb = nc * 256 + nq + jh * 32;
                const int gate = colb >> 8;
                const int w2   = (colb & 255) >> 5;
                short8 pk;
#pragma unroll
                for (int rg = 0; rg < 4; rg++)
#pragma unroll
                    for (int s = 0; s < 2; s++) {
                        int col = colb + s * 16 + lc;
                        float v = acc[i][jh * 2 + s][rg] + bi[col];
                        pk[rg * 2 + s] = (short)f2bf(v);
                    }
                size_t dst = (size_t)gate * GIPL +
                             (((size_t)(t * 16 + g) * 512) + (size_t)w2 * 64 +
                              (size_t)rowg2 * 16 + lc) * 8;
                *(short8*)(out + dst) = pk;
            }
        }
    }
}

// ---------------------------------------------------------------------------
// G3: [a|c] = relu(y @ [W_a|W_c1] + b). ZERO LDS, zero barriers.
// 2048 blocks x 64 rows, 512 threads (8 waves 2m x 4n); frags direct.
// ---------------------------------------------------------------------------
__global__ __launch_bounds__(512, 4) void k_gemm_ac(
    const unsigned short* __restrict__ y, const unsigned short* __restrict__ WacT,
    const float* __restrict__ b_a, const float* __restrict__ b_c1,
    unsigned short* __restrict__ out)
{
    const int tid = threadIdx.x, w = tid >> 6, L = tid & 63;
    const int mq = (w >> 2) * 32, nq = (w & 3) * 64;
    const int m0 = blockIdx.x * 64;
    const int lc = L & 15, g8 = (L >> 4) * 8, lr = (L >> 4) * 4;

    const unsigned short* a0p = y + (size_t)(m0 + mq + lc) * 256 + g8;
    const unsigned short* a1p = y + (size_t)(m0 + mq + 16 + lc) * 256 + g8;

    for (int nc = 0; nc < 2; nc++) {
        f32x4 acc[2][4];
#pragma unroll
        for (int i = 0; i < 2; i++)
#pragma unroll
            for (int j = 0; j < 4; j++) acc[i][j] = 0;

#pragma unroll 2
        for (int kk = 0; kk < 256; kk += 32) {
            short8 a[2], b[4];
            a[0] = *(const short8*)(a0p + kk);
            a[1] = *(const short8*)(a1p + kk);
#pragma unroll
            for (int j = 0; j < 4; j++)
                b[j] = *(const short8*)(WacT + (size_t)(nc * 256 + nq + j * 16 + lc) * 256 + kk + g8);
#pragma unroll
            for (int i = 0; i < 2; i++)
#pragma unroll
                for (int j = 0; j < 4; j++)
                    acc[i][j] = __builtin_amdgcn_mfma_f32_16x16x32_bf16(a[i], b[j], acc[i][j], 0, 0, 0);
        }
#pragma unroll
        for (int i = 0; i < 2; i++)
#pragma unroll
            for (int j = 0; j < 4; j++) {
                int col = nc * 256 + nq + j * 16 + lc;
                float bv = (col < 256) ? b_a[col] : b_c1[col - 256];
#pragma unroll
                for (int rg = 0; rg < 4; rg++) {
                    int row = m0 + mq + i * 16 + lr + rg;
                    out[(size_t)row * 512 + col] = f2bf(fmaxf(acc[i][j][rg] + bv, 0.f));
                }
            }
    }
}

// ---------------------------------------------------------------------------
// GRU main pass: 256 WGs = (batch-tile g = x&15) x (chunk c = x>>4).
// Speculates carry-in = 0 for c>0 (chunk 0 uses true h0). Stores h_end[c].
// gi: 3x short8 per thread per step, prefetched one step ahead.
// y:  staged in LDS, stored as one 16B full-line write per thread per step.
// ---------------------------------------------------------------------------
__global__ __launch_bounds__(512, 1) void k_gru_main(
    const unsigned short* __restrict__ gi, const unsigned short* __restrict__ WhF,
    const int* __restrict__ dones, const float* __restrict__ h0,
    const float* __restrict__ bhn, unsigned short* __restrict__ y,
    unsigned short* __restrict__ hend)
{
    __shared__ unsigned short hT[2][16][264];
    __shared__ unsigned short yS[2][16][256];
    __shared__ unsigned int rowbits[16];      // bit t' of dones for each row
    const int tid = threadIdx.x, w = tid >> 6, L = tid & 63;
    const int g = blockIdx.x & 15, c = blockIdx.x >> 4;
    const int b0 = g * 16, t0 = c * CHUNK;
    const int rowg = L >> 4, lc = L & 15;

    short8 Bf[6][8];
#pragma unroll
    for (int i6 = 0; i6 < 6; i6++)
#pragma unroll
        for (int ks = 0; ks < 8; ks++)
            Bf[i6][ks] = *(const short8*)(WhF + ((((size_t)w * 6 + i6) * 8 + ks) * 64 + L) * 8);

    const float bh0 = bhn[w * 32 + lc], bh1 = bhn[w * 32 + 16 + lc];

    // build dones bitmask for this chunk
    if (tid < 16) rowbits[tid] = 0;
    __syncthreads();
    {
        int tp = tid >> 4, r = tid & 15;
        if (dones[(t0 + tp) * 256 + b0 + r]) atomicOr(&rowbits[r], 1u << tp);
    }
    __syncthreads();

    unsigned rbr[4];
#pragma unroll
    for (int r = 0; r < 4; r++) rbr[r] = rowbits[rowg * 4 + r];

    // init h: c==0 -> h0 with done[0] reset; c>0 -> speculative 0
    {
        int hrow = tid >> 5, hcol = (tid & 31) * 8;
        bool rz = (rowbits[hrow] & 1u) != 0;
#pragma unroll
        for (int cc = 0; cc < 8; cc++) {
            unsigned short v = 0;
            if (c == 0 && !rz) v = f2bf(h0[(b0 + hrow) * 256 + hcol + cc]);
            hT[0][hrow][hcol + cc] = v;
        }
    }
    __syncthreads();

    // gi packed base for this thread: ((t*16+g)*512 + tid)*8, t = t0+tp
    const size_t gstep = (size_t)16 * 512 * 8;
    size_t gb = ((size_t)(t0 * 16 + g) * 512 + tid) * 8;
    short8 vir = *(const short8*)(gi + gb);
    short8 viz = *(const short8*)(gi + GIPL + gb);
    short8 vin = *(const short8*)(gi + 2 * GIPL + gb);

#pragma unroll 2
    for (int tp = 0; tp < CHUNK; tp++) {
        const int cur = tp & 1, nxt = cur ^ 1;
        const int t = t0 + tp;

        // prefetch next step's gi (independent of h)
        short8 nir, niz, nin;
        if (tp + 1 < CHUNK) {
            size_t gn = gb + (size_t)(tp + 1) * gstep;
            nir = *(const short8*)(gi + gn);
            niz = *(const short8*)(gi + GIPL + gn);
            nin = *(const short8*)(gi + 2 * GIPL + gn);
        }

        f32x4 acc0 = 0, acc1 = 0, acc2 = 0, acc3 = 0, acc4 = 0, acc5 = 0;
#pragma unroll
        for (int ks = 0; ks < 8; ks++) {
            short8 a = *(const short8*)&hT[cur][lc][ks * 32 + rowg * 8];
            acc0 = __builtin_amdgcn_mfma_f32_16x16x32_bf16(a, Bf[0][ks], acc0, 0, 0, 0);
            acc1 = __builtin_amdgcn_mfma_f32_16x16x32_bf16(a, Bf[1][ks], acc1, 0, 0, 0);
            acc2 = __builtin_amdgcn_mfma_f32_16x16x32_bf16(a, Bf[2][ks], acc2, 0, 0, 0);
            acc3 = __builtin_amdgcn_mfma_f32_16x16x32_bf16(a, Bf[3][ks], acc3, 0, 0, 0);
            acc4 = __builtin_amdgcn_mfma_f32_16x16x32_bf16(a, Bf[4][ks], acc4, 0, 0, 0);
            acc5 = __builtin_amdgcn_mfma_f32_16x16x32_bf16(a, Bf[5][ks], acc5, 0, 0, 0);
        }

#pragma unroll
        for (int s = 0; s < 2; s++) {
            const int j = w * 32 + s * 16 + lc;
            f32x4 hrv = s ? acc1 : acc0;
            f32x4 hzv = s ? acc3 : acc2;
            f32x4 hnv = s ? acc5 : acc4;
            float bh = s ? bh1 : bh0;
#pragma unroll
            for (int r = 0; r < 4; r++) {
                int row = rowg * 4 + r;
                float ir  = bf2f((unsigned short)vir[r * 2 + s]);
                float iz  = bf2f((unsigned short)viz[r * 2 + s]);
                float inn = bf2f((unsigned short)vin[r * 2 + s]);
                float ho  = bf2f(hT[cur][row][j]);
                unsigned short hb = gru_cell(ir, iz, inn, ho, hrv[r], hzv[r], hnv[r], bh);
                yS[cur][row][j] = hb;
                unsigned short hw = hb;
                if (tp + 1 < CHUNK && ((rbr[r] >> (tp + 1)) & 1u)) hw = 0;
                hT[nxt][row][j] = hw;
            }
        }
        __syncthreads();

        // coalesced y store (one 16B full-line write per thread)
        {
            int yrow = tid >> 5, ycol = (tid & 31) * 8;
            short8 yv = *(const short8*)&yS[cur][yrow][ycol];
            *(short8*)(y + ((size_t)t * 256 + b0 + yrow) * 256 + ycol) = yv;
            if (tp == CHUNK - 1)
                *(short8*)(hend + ((size_t)c * 256 + b0 + yrow) * 256 + ycol) = yv;
        }

        vir = nir; viz = niz; vin = nin;
    }
}

// ---------------------------------------------------------------------------
// PARALLEL GRU fixup: 240 WGs = (chunk c=1..15) x (16 batch-tiles).
// Carry-in = speculative hend[c-1], exact for rows with >=1 done in c-1.
// Violation (prob 2^-32/row/chunk) raises *flag -> sequential fallback.
// ---------------------------------------------------------------------------
__global__ __launch_bounds__(512, 1) void k_gru_fix_par(
    const unsigned short* __restrict__ gi, const unsigned short* __restrict__ WhF,
    const int* __restrict__ dones, const float* __restrict__ bhn,
    const unsigned short* __restrict__ hend, unsigned short* __restrict__ y,
    int* __restrict__ flag)
{
    __shared__ unsigned short hT[2][16][264];
    __shared__ unsigned int rowbits[16], prevbits[16];
    __shared__ int sh_fd[16];
    const int tid = threadIdx.x, w = tid >> 6, L = tid & 63;
    const int g = blockIdx.x & 15, c = (blockIdx.x >> 4) + 1;
    const int b0 = g * 16, t0 = c * CHUNK;
    const int rowg = L >> 4, lc = L & 15;
    const int hrow = tid >> 5, hcol = (tid & 31) * 8;

    short8 Bf[6][8];
#pragma unroll
    for (int i6 = 0; i6 < 6; i6++)
#pragma unroll
        for (int ks = 0; ks < 8; ks++)
            Bf[i6][ks] = *(const short8*)(WhF + ((((size_t)w * 6 + i6) * 8 + ks) * 64 + L) * 8);

    const float bh0 = bhn[w * 32 + lc], bh1 = bhn[w * 32 + 16 + lc];

    if (tid < 16) { rowbits[tid] = 0; prevbits[tid] = 0; }
    __syncthreads();
    {
        int tp = tid >> 4, r = tid & 15;
        if (dones[(t0 + tp) * 256 + b0 + r])         atomicOr(&rowbits[r],  1u << tp);
        if (dones[(t0 - CHUNK + tp) * 256 + b0 + r]) atomicOr(&prevbits[r], 1u << tp);
    }
    __syncthreads();
    if (tid < 16) {
        unsigned m = rowbits[tid];
        sh_fd[tid] = m ? __builtin_ctz(m) : CHUNK;
        if (prevbits[tid] == 0) atomicOr(flag, 1);   // carry-in untrusted
    }
    __syncthreads();

    int maxfix = 0;
    unsigned rbr[4]; int fdr[4];
#pragma unroll
    for (int r = 0; r < 16; r++) maxfix = max(maxfix, sh_fd[r]);
    if (maxfix == 0) return;                          // all rows reset at step 0
#pragma unroll
    for (int r = 0; r < 4; r++) {
        rbr[r] = rowbits[rowg * 4 + r];
        fdr[r] = sh_fd[rowg * 4 + r];
    }

    // carry-in: speculative end of chunk c-1, with chunk-c step-0 reset
    {
        short8 hv = *(const short8*)(hend + ((size_t)(c - 1) * 256 + b0 + hrow) * 256 + hcol);
        if (rowbits[hrow] & 1u) { short8 z = {0,0,0,0,0,0,0,0}; hv = z; }
        *(short8*)&hT[0][hrow][hcol] = hv;
    }
    __syncthreads();

    const size_t gstep = (size_t)16 * 512 * 8;
    const size_t gb0 = ((size_t)(t0 * 16 + g) * 512 + tid) * 8;

    int cur = 0;
    for (int tp = 0; tp < maxfix; tp++) {
        const int nxt = cur ^ 1;

        f32x4 acc0 = 0, acc1 = 0, acc2 = 0, acc3 = 0, acc4 = 0, acc5 = 0;
#pragma unroll
        for (int ks = 0; ks < 8; ks++) {
            short8 a = *(const short8*)&hT[cur][lc][ks * 32 + rowg * 8];
            acc0 = __builtin_amdgcn_mfma_f32_16x16x32_bf16(a, Bf[0][ks], acc0, 0, 0, 0);
            acc1 = __builtin_amdgcn_mfma_f32_16x16x32_bf16(a, Bf[1][ks], acc1, 0, 0, 0);
            acc2 = __builtin_amdgcn_mfma_f32_16x16x32_bf16(a, Bf[2][ks], acc2, 0, 0, 0);
            acc3 = __builtin_amdgcn_mfma_f32_16x16x32_bf16(a, Bf[3][ks], acc3, 0, 0, 0);
            acc4 = __builtin_amdgcn_mfma_f32_16x16x32_bf16(a, Bf[4][ks], acc4, 0, 0, 0);
            acc5 = __builtin_amdgcn_mfma_f32_16x16x32_bf16(a, Bf[5][ks], acc5, 0, 0, 0);
        }

        size_t gb = gb0 + (size_t)tp * gstep;
        short8 vir = *(const short8*)(gi + gb);
        short8 viz = *(const short8*)(gi + GIPL + gb);
        short8 vin = *(const short8*)(gi + 2 * GIPL + gb);

        unsigned short* yb = y + (size_t)((t0 + tp) * 256 + b0) * 256;
#pragma unroll
        for (int s = 0; s < 2; s++) {
            const int j = w * 32 + s * 16 + lc;
            f32x4 hrv = s ? acc1 : acc0;
            f32x4 hzv = s ? acc3 : acc2;
            f32x4 hnv = s ? acc5 : acc4;
            float bh = s ? bh1 : bh0;
#pragma unroll
            for (int r = 0; r < 4; r++) {
                int row = rowg * 4 + r;
                float ir  = bf2f((unsigned short)vir[r * 2 + s]);
                float iz  = bf2f((unsigned short)viz[r * 2 + s]);
                float inn = bf2f((unsigned short)vin[r * 2 + s]);
                float ho  = bf2f(hT[cur][row][j]);
                unsigned short hb = gru_cell(ir, iz, inn, ho, hrv[r], hzv[r], hnv[r], bh);
                if (tp < fdr[r]) yb[row * 256 + j] = hb;   // only fix wrong prefix
                unsigned short hw = hb;
                if (tp + 1 < CHUNK && ((rbr[r] >> (tp + 1)) & 1u)) hw = 0;
                hT[nxt][row][j] = hw;
            }
        }
        __syncthreads();
        cur = nxt;
    }
}

// ---------------------------------------------------------------------------
// GRU fixup FALLBACK (sequential over chunks): only runs if flag was set.
// ---------------------------------------------------------------------------
__global__ __launch_bounds__(512, 1) void k_gru_fix(
    const unsigned short* __restrict__ gi, const unsigned short* __restrict__ WhF,
    const int* __restrict__ dones, const float* __restrict__ bhn,
    const unsigned short* __restrict__ hend, unsigned short* __restrict__ y,
    const int* __restrict__ flag)
{
    if (*flag == 0) return;                   // uniform: common case, exit fast

    __shared__ unsigned short hT[2][16][264];
    __shared__ unsigned int rowbits[16];
    __shared__ int sh_fd[16];
    const int tid = threadIdx.x, w = tid >> 6, L = tid & 63;
    const int b0 = blockIdx.x * 16, g = blockIdx.x;
    const int rowg = L >> 4, lc = L & 15;
    const int hrow = tid >> 5, hcol = (tid & 31) * 8;

    short8 Bf[6][8];
#pragma unroll
    for (int i6 = 0; i6 < 6; i6++)
#pragma unroll
        for (int ks = 0; ks < 8; ks++)
            Bf[i6][ks] = *(const short8*)(WhF + ((((size_t)w * 6 + i6) * 8 + ks) * 64 + L) * 8);

    const float bh0 = bhn[w * 32 + lc], bh1 = bhn[w * 32 + 16 + lc];

    // carry = corrected end of chunk 0 (chunk 0 speculation used true h0)
    *(short8*)&hT[0][hrow][hcol] =
        *(const short8*)(hend + (size_t)(b0 + hrow) * 256 + hcol);
    int cur = 0;

    const size_t gstep = (size_t)16 * 512 * 8;

    for (int c = 1; c < NCH; c++) {
        const int t0 = c * CHUNK;
        if (tid < 16) rowbits[tid] = 0;
        __syncthreads();
        {
            int tp = tid >> 4, r = tid & 15;
            if (dones[(t0 + tp) * 256 + b0 + r]) atomicOr(&rowbits[r], 1u << tp);
        }
        __syncthreads();
        if (tid < 16) {
            unsigned m = rowbits[tid];
            sh_fd[tid] = m ? __builtin_ctz(m) : CHUNK;
        }
        __syncthreads();

        int maxfix = 0;
        unsigned rbr[4]; int fdr[4];
#pragma unroll
        for (int r = 0; r < 16; r++) maxfix = max(maxfix, sh_fd[r]);
#pragma unroll
        for (int r = 0; r < 4; r++) {
            rbr[r] = rowbits[rowg * 4 + r];
            fdr[r] = sh_fd[rowg * 4 + r];
        }
        // apply this chunk's step-0 reset to the carry
        if (rowbits[hrow] & 1u) {
#pragma unroll
            for (int cc = 0; cc < 8; cc++) hT[cur][hrow][hcol + cc] = 0;
        }
        __syncthreads();

        const size_t gb0 = ((size_t)(t0 * 16 + g) * 512 + tid) * 8;

        for (int tp = 0; tp < maxfix; tp++) {
            const int nxt = cur ^ 1;

            f32x4 acc0 = 0, acc1 = 0, acc2 = 0, acc3 = 0, acc4 = 0, acc5 = 0;
#pragma unroll
            for (int ks = 0; ks < 8; ks++) {
                short8 a = *(const short8*)&hT[cur][lc][ks * 32 + rowg * 8];
                acc0 = __builtin_amdgcn_mfma_f32_16x16x32_bf16(a, Bf[0][ks], acc0, 0, 0, 0);
                acc1 = __builtin_amdgcn_mfma_f32_16x16x32_bf16(a, Bf[1][ks], acc1, 0, 0, 0);
                acc2 = __builtin_amdgcn_mfma_f32_16x16x32_bf16(a, Bf[2][ks], acc2, 0, 0, 0);
                acc3 = __builtin_amdgcn_mfma_f32_16x16x32_bf16(a, Bf[3][ks], acc3, 0, 0, 0);
                acc4 = __builtin_amdgcn_mfma_f32_16x16x32_bf16(a, Bf[4][ks], acc4, 0, 0, 0);
                acc5 = __builtin_amdgcn_mfma_f32_16x16x32_bf16(a, Bf[5][ks], acc5, 0, 0, 0);
            }

            size_t gb = gb0 + (size_t)tp * gstep;
            short8 vir = *(const short8*)(gi + gb);
            short8 viz = *(const short8*)(gi + GIPL + gb);
            short8 vin = *(const short8*)(gi + 2 * GIPL + gb);

            unsigned short* yb = y + (size_t)((t0 + tp) * 256 + b0) * 256;
#pragma unroll
            for (int s = 0; s < 2; s++) {
                const int j = w * 32 + s * 16 + lc;
                f32x4 hrv = s ? acc1 : acc0;
                f32x4 hzv = s ? acc3 : acc2;
                f32x4 hnv = s ? acc5 : acc4;
                float bh = s ? bh1 : bh0;
#pragma unroll
                for (int r = 0; r < 4; r++) {
                    int row = rowg * 4 + r;
                    float ir  = bf2f((unsigned short)vir[r * 2 + s]);
                    float iz  = bf2f((unsigned short)viz[r * 2 + s]);
                    float inn = bf2f((unsigned short)vin[r * 2 + s]);
                    float ho  = bf2f(hT[cur][row][j]);
                    unsigned short hb = gru_cell(ir, iz, inn, ho, hrv[r], hzv[r], hnv[r], bh);
                    if (tp < fdr[r]) yb[row * 256 + j] = hb;   // only fix wrong prefix
                    unsigned short hw = hb;
                    if (tp + 1 < CHUNK && ((rbr[r] >> (tp + 1)) & 1u)) hw = 0;
                    hT[nxt][row][j] = hw;
                }
            }
            __syncthreads();
            cur = nxt;
        }

        // splice: rows that saw a done have correct speculative h_end
        if (sh_fd[hrow] < CHUNK) {
            *(short8*)&hT[cur][hrow][hcol] =
                *(const short8*)(hend + ((size_t)c * 256 + b0 + hrow) * 256 + hcol);
        }
        __syncthreads();
    }
}

// ---------------------------------------------------------------------------
// G4: logits. ZERO LDS, zero barriers; frags direct from global.
// 1024 blocks x 128 rows, 256 threads (4 m-waves), acc[2][10].
// ---------------------------------------------------------------------------
__global__ __launch_bounds__(256, 2) void k_logits(
    const unsigned short* __restrict__ ac, const unsigned short* __restrict__ Bt,
    const float* __restrict__ blog,
    const int* __restrict__ av1, const int* __restrict__ av2,
    const int* __restrict__ av3, const int* __restrict__ av4,
    float* __restrict__ outp)
{
    const int tid = threadIdx.x, w = tid >> 6, L = tid & 63;
    const int m0 = blockIdx.x * 128;
    const int lc = L & 15, g8 = (L >> 4) * 8, lr = (L >> 4) * 4;

    f32x4 acc[2][10];
#pragma unroll
    for (int i = 0; i < 2; i++)
#pragma unroll
        for (int j = 0; j < 10; j++) acc[i][j] = 0;

    const unsigned short* a0p = ac + (size_t)(m0 + w * 32 + lc) * 512 + g8;
    const unsigned short* a1p = ac + (size_t)(m0 + w * 32 + 16 + lc) * 512 + g8;

#pragma unroll 2
    for (int kk = 0; kk < 256; kk += 32) {
        short8 a[2], b[10];
        a[0] = *(const short8*)(a0p + kk);
        a[1] = *(const short8*)(a1p + kk);
#pragma unroll
        for (int j = 0; j < 10; j++)
            b[j] = *(const short8*)(Bt + (size_t)(j * 16 + lc) * 256 + kk + g8);
#pragma unroll
        for (int i = 0; i < 2; i++)
#pragma unroll
            for (int j = 0; j < 10; j++)
                acc[i][j] = __builtin_amdgcn_mfma_f32_16x16x32_bf16(a[i], b[j], acc[i][j], 0, 0, 0);
    }
#pragma unroll
    for (int j = 0; j < 10; j++) {
        int col = j * 16 + lc;
        if (col >= 144) continue;
        int gbase, adim; const int* av; size_t obase;
        if      (col < 32) { gbase = 0;  adim = 32; av = av1; obase = OUT_LC1; }
        else if (col < 64) { gbase = 32; adim = 32; av = av2; obase = OUT_LC2; }
        else if (col < 80) { gbase = 64; adim = 16; av = av3; obase = OUT_MC;  }
        else               { gbase = 80; adim = 64; av = av4; obase = OUT_HINT;}
        int cof = col - gbase;
        float bv = blog[col];
#pragma unroll
        for (int i = 0; i < 2; i++)
#pragma unroll
            for (int rg = 0; rg < 4; rg++) {
                int R = m0 + w * 32 + i * 16 + lr + rg;
                float v = acc[i][j][rg] + bv;
                int a_ = av[(size_t)R * adim + cof];
                v -= (1.f - (float)a_) * 1e10f;
                outp[obase + (size_t)R * adim + cof] = v;
            }
    }
}

// ---------------------------------------------------------------------------
// G5: critic (unchanged)
// ---------------------------------------------------------------------------
__global__ __launch_bounds__(256, 4) void k_critic(
    const unsigned short* __restrict__ ac, const float* __restrict__ W_c2,
    const float* __restrict__ b_c2, float* __restrict__ outp)
{
    const int tid = threadIdx.x, w = tid >> 6, L = tid & 63;
    f32x4 wv = *(const f32x4*)(W_c2 + L * 4);
    float bb = b_c2[0];
    int base = blockIdx.x * 64 + w * 16;
    for (int rr = 0; rr < 16; rr++) {
        int R = base + rr;
        const unsigned short* p = ac + (size_t)R * 512 + 256 + L * 4;
        float s = bf2f(p[0]) * wv[0] + bf2f(p[1]) * wv[1] +
                  bf2f(p[2]) * wv[2] + bf2f(p[3]) * wv[3];
#pragma unroll
        for (int o = 32; o > 0; o >>= 1) s += __shfl_down(s, o);
        if (L == 0) outp[OUT_CRIT + R] = s + bb;
    }
}

__global__ __launch_bounds__(256, 4) void k_hidden(
    const unsigned short* __restrict__ y, float* __restrict__ outp)
{
    int i = blockIdx.x * 256 + threadIdx.x;
    outp[OUT_HID + i] = bf2f(y[(size_t)511 * 65536 + i]);
}

// ---------------------------------------------------------------------------
extern "C" void kernel_launch(void* const* d_in, const int* in_sizes, int n_in,
                              void* d_out, int out_size, void* d_ws, size_t ws_size,
                              hipStream_t stream)
{
    const float* hidden = (const float*)d_in[0];
    const float* obs    = (const float*)d_in[1];
    const int*   dones  = (const int*)d_in[2];
    const int*   av1    = (const int*)d_in[3];
    const int*   av2    = (const int*)d_in[4];
    const int*   av3    = (const int*)d_in[5];
    const int*   av4    = (const int*)d_in[6];
    const float* W_emb  = (const float*)d_in[7];
    const float* b_emb  = (const float*)d_in[8];
    const float* Wi     = (const float*)d_in[9];
    const float* bi     = (const float*)d_in[10];
    const float* Wh     = (const float*)d_in[11];
    const float* bhn    = (const float*)d_in[12];
    const float* W_a    = (const float*)d_in[13];
    const float* b_a    = (const float*)d_in[14];
    const float* W_lc1  = (const float*)d_in[15];
    const float* b_lc1  = (const float*)d_in[16];
    const float* W_lc2  = (const float*)d_in[17];
    const float* b_lc2  = (const float*)d_in[18];
    const float* W_mc   = (const float*)d_in[19];
    const float* b_mc   = (const float*)d_in[20];
    const float* W_hint = (const float*)d_in[21];
    const float* b_hint = (const float*)d_in[22];
    const float* W_c1   = (const float*)d_in[23];
    const float* b_c1   = (const float*)d_in[24];
    const float* W_c2   = (const float*)d_in[25];
    const float* b_c2   = (const float*)d_in[26];

    char* ws = (char*)d_ws;
    unsigned short* WembT = (unsigned short*)(ws + 0);
    unsigned short* WiT   = (unsigned short*)(ws + 262144);
    unsigned short* WhF   = (unsigned short*)(ws + 655360);
    unsigned short* WacT  = (unsigned short*)(ws + 1048576);
    unsigned short* WlogT = (unsigned short*)(ws + 1310720);
    float*          blog  = (float*)(ws + 1392640);
    int*            fflag = (int*)(ws + 1393280);
    // hend (2 MB) / ac (134 MB) share a region. hend lives gru_main->gru_fix;
    // ac written by G3 after fixup.
    unsigned short* hend  = (unsigned short*)(ws + 1393664);
    unsigned short* ac    = hend;
    unsigned short* gibuf = (unsigned short*)(ws + 135611392);
    unsigned short* ybuf  = (unsigned short*)(ws + 336937984);
    float* outp = (float*)d_out;

    k_prep<<<2721, 256, 0, stream>>>(W_emb, Wi, Wh, W_a, W_c1, W_lc1, W_lc2,
                                     W_mc, W_hint, b_lc1, b_lc2, b_mc, b_hint,
                                     WembT, WiT, WhF, WacT, WlogT, blog, fflag);
    k_fused_g12<<<2048, 512, 0, stream>>>(obs, WembT, b_emb, WiT, bi, gibuf);
    k_gru_main<<<256, 512, 0, stream>>>(gibuf, WhF, dones, hidden, bhn, ybuf, hend);
    k_gru_fix_par<<<240, 512, 0, stream>>>(gibuf, WhF, dones, bhn, hend, ybuf, fflag);
    k_gru_fix<<<16, 512, 0, stream>>>(gibuf, WhF, dones, bhn, hend, ybuf, fflag);
    k_gemm_ac<<<2048, 512, 0, stream>>>(ybuf, WacT, b_a, b_c1, ac);
    k_logits<<<1024, 256, 0, stream>>>(ac, WlogT, blog, av1, av2, av3, av4, outp);
    k_critic<<<2048, 256, 0, stream>>>(ac, W_c2, b_c2, outp);
    k_hidden<<<2048 / 8, 256, 0, stream>>>(ybuf, outp);
}

// Round 5
// 873.578 us; speedup vs baseline: 1.4337x; 1.4337x over previous
//
#include <hip/hip_runtime.h>
#include <stdint.h>

// ---------------------------------------------------------------------------
// ActorCriticRNN on MI355X.
//   prep:  weights -> bf16 FRAGMENT-LINEAR layouts (WembF/WiF/WacF/WlogF/WhF):
//          each MFMA B-fragment is 64 lanes x 16B contiguous -> one 1KB burst,
//          L2-resident. (R4 lesson: direct frag loads from row-major B touch
//          16 segments/instr and become request-rate bound.)
//   G12:   FUSED: phase 1 emb = relu(obs @ W_emb + b) with As staged in LDS
//          (fp32->bf16 conversion), B direct from WembF. emb -> eS (LDS).
//          phase 2: gi = eS @ WiF + bi, ZERO barriers, packed gate-plane out.
//   GRU:   chunk-parallel speculation (verified R2/R3 version).
//   G3:    k_gemm_ac: yS staged once (1 barrier), WacF direct.
//   G4:    k_logits: As staged, WlogF direct. G5: critic dot. out0: hidden.
// ---------------------------------------------------------------------------

typedef short short8 __attribute__((ext_vector_type(8)));
typedef float f32x4  __attribute__((ext_vector_type(4)));

#define T_DIM 512
#define CHUNK 32
#define NCH   16
#define GIPL  ((size_t)33554432)   // gi gate-plane size in shorts (8192*512*8)

// output offsets (fp32 elements)
#define OUT_HID  ((size_t)0)
#define OUT_LC1  ((size_t)65536)
#define OUT_LC2  ((size_t)4259840)
#define OUT_MC   ((size_t)8454144)
#define OUT_HINT ((size_t)10551296)
#define OUT_CRIT ((size_t)18939904)

__device__ __forceinline__ unsigned short f2bf(float f) {
    unsigned u = __float_as_uint(f);
    u += 0x7fffu + ((u >> 16) & 1u);          // round-to-nearest-even
    return (unsigned short)(u >> 16);
}
__device__ __forceinline__ float bf2f(unsigned short h) {
    return __uint_as_float(((unsigned)h) << 16);
}

__device__ __forceinline__ unsigned short gru_cell(
    float ir, float iz, float inn, float ho,
    float hrv, float hzv, float hnv, float bh)
{
    float rg = 1.f / (1.f + __expf(-(ir + hrv)));
    float z  = 1.f / (1.f + __expf(-(iz + hzv)));
    float ex = __expf(2.f * (inn + rg * (hnv + bh)));
    float n  = 1.f - 2.f / (ex + 1.f);        // tanh, inf-safe
    return f2bf((1.f - z) * n + z * ho);
}

// ---------------------------------------------------------------------------
// prep: all weights to fragment-linear bf16.
// Fragment element convention (matches in-kernel MFMA usage everywhere):
//   lane L, elem jj ->  n = nbase + (L&15),  k = kbase + ((L>>4)<<3) + jj
// ---------------------------------------------------------------------------
__global__ __launch_bounds__(256, 4) void k_prep(
    const float* __restrict__ W_emb, const float* __restrict__ Wi,
    const float* __restrict__ Wh,    const float* __restrict__ W_a,
    const float* __restrict__ W_c1,  const float* __restrict__ W_lc1,
    const float* __restrict__ W_lc2, const float* __restrict__ W_mc,
    const float* __restrict__ W_hint,
    const float* __restrict__ b_lc1, const float* __restrict__ b_lc2,
    const float* __restrict__ b_mc,  const float* __restrict__ b_hint,
    unsigned short* __restrict__ WembF, unsigned short* __restrict__ WiF,
    unsigned short* __restrict__ WhF,   unsigned short* __restrict__ WacF,
    unsigned short* __restrict__ WlogF, float* __restrict__ blog,
    int* __restrict__ fixflag)
{
    int i = blockIdx.x * 256 + threadIdx.x;
    if (i < 131072) {                         // WembF: frag (q, j, kt32)
        int jj = i & 7, L = (i >> 3) & 63, kt32 = (i >> 9) & 15;
        int j = (i >> 13) & 3, q = (i >> 15) & 3;
        int n = q * 64 + j * 16 + (L & 15);
        int k = kt32 * 32 + ((L >> 4) << 3) + jj;
        WembF[i] = f2bf(W_emb[k * 256 + n]);
        return;
    }
    i -= 131072;
    if (i < 196608) {                         // WiF: frag (nc, q, j, kk32)
        int jj = i & 7, L = (i >> 3) & 63, kk32 = (i >> 9) & 7;
        int j = (i >> 12) & 3, q = (i >> 14) & 3, nc = i >> 16;
        int n = nc * 256 + q * 64 + j * 16 + (L & 15);
        int k = kk32 * 32 + ((L >> 4) << 3) + jj;
        WiF[i] = f2bf(Wi[k * 768 + n]);
        return;
    }
    i -= 196608;
    if (i < 196608) {                         // Wh fragment-linear (GRU, verified)
        int jj = i & 7, L = (i >> 3) & 63, ks = (i >> 9) & 7, rest = i >> 12;
        int w = rest / 6, i6 = rest % 6, rho = i6 >> 1, s = i6 & 1;
        int k   = ks * 32 + ((L >> 4) << 3) + jj;
        int col = rho * 256 + w * 32 + s * 16 + (L & 15);
        WhF[i] = f2bf(Wh[k * 768 + col]);
        return;
    }
    i -= 196608;
    if (i < 131072) {                         // WacF: frag (nc, q, j, kk32)
        int jj = i & 7, L = (i >> 3) & 63, kk32 = (i >> 9) & 7;
        int j = (i >> 12) & 3, q = (i >> 14) & 3, nc = (i >> 16) & 1;
        int n = nc * 256 + q * 64 + j * 16 + (L & 15);
        int k = kk32 * 32 + ((L >> 4) << 3) + jj;
        WacF[i] = f2bf(n < 256 ? W_a[k * 256 + n] : W_c1[k * 256 + (n - 256)]);
        return;
    }
    i -= 131072;
    if (i < 40960) {                          // WlogF: frag (j, kk32), N pad 160
        int jj = i & 7, L = (i >> 3) & 63, kk32 = (i >> 9) & 7;
        int j = i >> 12;                      // 0..9
        int n = j * 16 + (L & 15);
        int k = kk32 * 32 + ((L >> 4) << 3) + jj;
        float v;
        if      (n < 32)  v = W_lc1[k * 32 + n];
        else if (n < 64)  v = W_lc2[k * 32 + (n - 32)];
        else if (n < 80)  v = W_mc [k * 16 + (n - 64)];
        else if (n < 144) v = W_hint[k * 64 + (n - 80)];
        else              v = 0.f;
        WlogF[i] = f2bf(v);
        return;
    }
    i -= 40960;
    if (i < 160) {
        float v;
        if      (i < 32)  v = b_lc1[i];
        else if (i < 64)  v = b_lc2[i - 32];
        else if (i < 80)  v = b_mc [i - 64];
        else if (i < 144) v = b_hint[i - 80];
        else              v = 0.f;
        blog[i] = v;
        return;
    }
    i -= 160;
    if (i == 0) *fixflag = 0;
}

// ---------------------------------------------------------------------------
// FUSED G1+G2. 2048 blocks x 64 rows, 512 threads = 8 waves (2m x 4n).
//   phase 1: As (obs->bf16) staged per kt (2 barriers x 8), B-frags direct
//            from WembF (1KB bursts, L2-hot). relu+bias -> eS. 1 barrier.
//   phase 2: 3 gate chunks, a from eS (LDS), b direct from WiF. ZERO barriers.
//            Packed gate-plane epilogue (verified formulas).
// ---------------------------------------------------------------------------
__global__ __launch_bounds__(512, 3) void k_fused_g12(
    const float* __restrict__ obs, const unsigned short* __restrict__ WembF,
    const float* __restrict__ b_emb, const unsigned short* __restrict__ WiF,
    const float* __restrict__ bi, unsigned short* __restrict__ out)
{
    __shared__ unsigned short As[64][72];
    __shared__ unsigned short eS[64][264];
    const int tid = threadIdx.x, w = tid >> 6, L = tid & 63;
    const int mq = (w >> 2) * 32, wq = w & 3, nq = wq * 64;
    const int m0 = blockIdx.x * 64;
    const int lc = L & 15, lq8 = (L >> 4) * 8, lr = (L >> 4) * 4;
    const int sra = tid >> 3, sha = (tid & 7) * 8;   // As staging: 8 thr/row

    f32x4 acc[2][4];
#pragma unroll
    for (int i = 0; i < 2; i++)
#pragma unroll
        for (int j = 0; j < 4; j++) acc[i][j] = 0;

    // ---- phase 1: acc = obs @ WembF ----
    const float* Ag = obs + (size_t)(m0 + sra) * 512 + sha;
    for (int kt = 0; kt < 512; kt += 64) {
        {
            f32x4 v0 = *(const f32x4*)(Ag + kt);
            f32x4 v1 = *(const f32x4*)(Ag + kt + 4);
            short8 pk;
            pk[0] = (short)f2bf(v0[0]); pk[1] = (short)f2bf(v0[1]);
            pk[2] = (short)f2bf(v0[2]); pk[3] = (short)f2bf(v0[3]);
            pk[4] = (short)f2bf(v1[0]); pk[5] = (short)f2bf(v1[1]);
            pk[6] = (short)f2bf(v1[2]); pk[7] = (short)f2bf(v1[3]);
            *(short8*)&As[sra][sha] = pk;
        }
        __syncthreads();
#pragma unroll
        for (int ks = 0; ks < 2; ks++) {
            const int kt32 = (kt >> 5) + ks;
            short8 a[2], b[4];
#pragma unroll
            for (int i = 0; i < 2; i++)
                a[i] = *(const short8*)&As[mq + i * 16 + lc][ks * 32 + lq8];
#pragma unroll
            for (int j = 0; j < 4; j++)
                b[j] = *(const short8*)(WembF +
                        ((((size_t)(wq * 4 + j) * 16 + kt32) * 64 + L) * 8));
#pragma unroll
            for (int i = 0; i < 2; i++)
#pragma unroll
                for (int j = 0; j < 4; j++)
                    acc[i][j] = __builtin_amdgcn_mfma_f32_16x16x32_bf16(a[i], b[j], acc[i][j], 0, 0, 0);
        }
        __syncthreads();
    }
    // epilogue phase 1: relu -> bf16 -> eS
#pragma unroll
    for (int i = 0; i < 2; i++)
#pragma unroll
        for (int j = 0; j < 4; j++) {
            int col = nq + j * 16 + lc;
            float bv = b_emb[col];
#pragma unroll
            for (int rg = 0; rg < 4; rg++) {
                int row = mq + i * 16 + lr + rg;
                eS[row][col] = f2bf(fmaxf(acc[i][j][rg] + bv, 0.f));
            }
        }
    __syncthreads();

    // ---- phase 2: gi = eS @ WiF + bi, 3 gate chunks, no barriers ----
    for (int nc = 0; nc < 3; nc++) {
#pragma unroll
        for (int i = 0; i < 2; i++)
#pragma unroll
            for (int j = 0; j < 4; j++) acc[i][j] = 0;

#pragma unroll 2
        for (int kk = 0; kk < 256; kk += 32) {
            const int kk32 = kk >> 5;
            short8 a[2], b[4];
#pragma unroll
            for (int i = 0; i < 2; i++)
                a[i] = *(const short8*)&eS[mq + i * 16 + lc][kk + lq8];
#pragma unroll
            for (int j = 0; j < 4; j++)
                b[j] = *(const short8*)(WiF +
                        ((((size_t)((nc * 4 + wq) * 4 + j) * 8 + kk32) * 64 + L) * 8));
#pragma unroll
            for (int i = 0; i < 2; i++)
#pragma unroll
                for (int j = 0; j < 4; j++)
                    acc[i][j] = __builtin_amdgcn_mfma_f32_16x16x32_bf16(a[i], b[j], acc[i][j], 0, 0, 0);
        }
        // packed epilogue (verified formulas)
#pragma unroll
        for (int i = 0; i < 2; i++) {
            const int row0  = m0 + mq + i * 16 + lr;
            const int t     = row0 >> 8;
            const int g     = (row0 >> 4) & 15;
            const int rowg2 = (row0 >> 2) & 3;
#pragma unroll
            for (int jh = 0; jh < 2; jh++) {
                const int colb = nc * 256 + nq + jh * 32;
                const int gate = colb >> 8;
                const int w2   = (colb & 255) >> 5;
                short8 pk;
#pragma unroll
                for (int rg = 0; rg < 4; rg++)
#pragma unroll
                    for (int s = 0; s < 2; s++) {
                        int col = colb + s * 16 + lc;
                        float v = acc[i][jh * 2 + s][rg] + bi[col];
                        pk[rg * 2 + s] = (short)f2bf(v);
                    }
                size_t dst = (size_t)gate * GIPL +
                             (((size_t)(t * 16 + g) * 512) + (size_t)w2 * 64 +
                              (size_t)rowg2 * 16 + lc) * 8;
                *(short8*)(out + dst) = pk;
            }
        }
    }
}

// ---------------------------------------------------------------------------
// G3: [a|c] = relu(y @ [W_a|W_c1] + b). 2048 blocks x 64 rows, 512 threads.
// yS staged ONCE (1 barrier); WacF direct. No other barriers.
// ---------------------------------------------------------------------------
__global__ __launch_bounds__(512, 3) void k_gemm_ac(
    const unsigned short* __restrict__ y, const unsigned short* __restrict__ WacF,
    const float* __restrict__ b_a, const float* __restrict__ b_c1,
    unsigned short* __restrict__ out)
{
    __shared__ unsigned short yS[64][264];
    const int tid = threadIdx.x, w = tid >> 6, L = tid & 63;
    const int mq = (w >> 2) * 32, wq = w & 3, nq = wq * 64;
    const int m0 = blockIdx.x * 64;
    const int lc = L & 15, lq8 = (L >> 4) * 8, lr = (L >> 4) * 4;

    // stage y tile once: 32 shorts/thread
    {
        int r = tid >> 3, cb = (tid & 7) * 32;
        const unsigned short* yg = y + (size_t)(m0 + r) * 256 + cb;
#pragma unroll
        for (int c = 0; c < 32; c += 8)
            *(short8*)&yS[r][cb + c] = *(const short8*)(yg + c);
    }
    __syncthreads();

    for (int nc = 0; nc < 2; nc++) {
        f32x4 acc[2][4];
#pragma unroll
        for (int i = 0; i < 2; i++)
#pragma unroll
            for (int j = 0; j < 4; j++) acc[i][j] = 0;

#pragma unroll 2
        for (int kk = 0; kk < 256; kk += 32) {
            const int kk32 = kk >> 5;
            short8 a[2], b[4];
#pragma unroll
            for (int i = 0; i < 2; i++)
                a[i] = *(const short8*)&yS[mq + i * 16 + lc][kk + lq8];
#pragma unroll
            for (int j = 0; j < 4; j++)
                b[j] = *(const short8*)(WacF +
                        ((((size_t)((nc * 4 + wq) * 4 + j) * 8 + kk32) * 64 + L) * 8));
#pragma unroll
            for (int i = 0; i < 2; i++)
#pragma unroll
                for (int j = 0; j < 4; j++)
                    acc[i][j] = __builtin_amdgcn_mfma_f32_16x16x32_bf16(a[i], b[j], acc[i][j], 0, 0, 0);
        }
#pragma unroll
        for (int i = 0; i < 2; i++)
#pragma unroll
            for (int j = 0; j < 4; j++) {
                int col = nc * 256 + nq + j * 16 + lc;
                float bv = (col < 256) ? b_a[col] : b_c1[col - 256];
#pragma unroll
                for (int rg = 0; rg < 4; rg++) {
                    int row = m0 + mq + i * 16 + lr + rg;
                    out[(size_t)row * 512 + col] = f2bf(fmaxf(acc[i][j][rg] + bv, 0.f));
                }
            }
    }
}

// ---------------------------------------------------------------------------
// GRU main pass (verified R2/R3 version)
// ---------------------------------------------------------------------------
__global__ __launch_bounds__(512, 1) void k_gru_main(
    const unsigned short* __restrict__ gi, const unsigned short* __restrict__ WhF,
    const int* __restrict__ dones, const float* __restrict__ h0,
    const float* __restrict__ bhn, unsigned short* __restrict__ y,
    unsigned short* __restrict__ hend)
{
    __shared__ unsigned short hT[2][16][264];
    __shared__ unsigned short yS[2][16][256];
    __shared__ unsigned int rowbits[16];      // bit t' of dones for each row
    const int tid = threadIdx.x, w = tid >> 6, L = tid & 63;
    const int g = blockIdx.x & 15, c = blockIdx.x >> 4;
    const int b0 = g * 16, t0 = c * CHUNK;
    const int rowg = L >> 4, lc = L & 15;

    short8 Bf[6][8];
#pragma unroll
    for (int i6 = 0; i6 < 6; i6++)
#pragma unroll
        for (int ks = 0; ks < 8; ks++)
            Bf[i6][ks] = *(const short8*)(WhF + ((((size_t)w * 6 + i6) * 8 + ks) * 64 + L) * 8);

    const float bh0 = bhn[w * 32 + lc], bh1 = bhn[w * 32 + 16 + lc];

    // build dones bitmask for this chunk
    if (tid < 16) rowbits[tid] = 0;
    __syncthreads();
    {
        int tp = tid >> 4, r = tid & 15;
        if (dones[(t0 + tp) * 256 + b0 + r]) atomicOr(&rowbits[r], 1u << tp);
    }
    __syncthreads();

    unsigned rbr[4];
#pragma unroll
    for (int r = 0; r < 4; r++) rbr[r] = rowbits[rowg * 4 + r];

    // init h: c==0 -> h0 with done[0] reset; c>0 -> speculative 0
    {
        int hrow = tid >> 5, hcol = (tid & 31) * 8;
        bool rz = (rowbits[hrow] & 1u) != 0;
#pragma unroll
        for (int cc = 0; cc < 8; cc++) {
            unsigned short v = 0;
            if (c == 0 && !rz) v = f2bf(h0[(b0 + hrow) * 256 + hcol + cc]);
            hT[0][hrow][hcol + cc] = v;
        }
    }
    __syncthreads();

    // gi packed base for this thread: ((t*16+g)*512 + tid)*8, t = t0+tp
    const size_t gstep = (size_t)16 * 512 * 8;
    size_t gb = ((size_t)(t0 * 16 + g) * 512 + tid) * 8;
    short8 vir = *(const short8*)(gi + gb);
    short8 viz = *(const short8*)(gi + GIPL + gb);
    short8 vin = *(const short8*)(gi + 2 * GIPL + gb);

#pragma unroll 2
    for (int tp = 0; tp < CHUNK; tp++) {
        const int cur = tp & 1, nxt = cur ^ 1;
        const int t = t0 + tp;

        // prefetch next step's gi (independent of h)
        short8 nir, niz, nin;
        if (tp + 1 < CHUNK) {
            size_t gn = gb + (size_t)(tp + 1) * gstep;
            nir = *(const short8*)(gi + gn);
            niz = *(const short8*)(gi + GIPL + gn);
            nin = *(const short8*)(gi + 2 * GIPL + gn);
        }

        f32x4 acc0 = 0, acc1 = 0, acc2 = 0, acc3 = 0, acc4 = 0, acc5 = 0;
#pragma unroll
        for (int ks = 0; ks < 8; ks++) {
            short8 a = *(const short8*)&hT[cur][lc][ks * 32 + rowg * 8];
            acc0 = __builtin_amdgcn_mfma_f32_16x16x32_bf16(a, Bf[0][ks], acc0, 0, 0, 0);
            acc1 = __builtin_amdgcn_mfma_f32_16x16x32_bf16(a, Bf[1][ks], acc1, 0, 0, 0);
            acc2 = __builtin_amdgcn_mfma_f32_16x16x32_bf16(a, Bf[2][ks], acc2, 0, 0, 0);
            acc3 = __builtin_amdgcn_mfma_f32_16x16x32_bf16(a, Bf[3][ks], acc3, 0, 0, 0);
            acc4 = __builtin_amdgcn_mfma_f32_16x16x32_bf16(a, Bf[4][ks], acc4, 0, 0, 0);
            acc5 = __builtin_amdgcn_mfma_f32_16x16x32_bf16(a, Bf[5][ks], acc5, 0, 0, 0);
        }

#pragma unroll
        for (int s = 0; s < 2; s++) {
            const int j = w * 32 + s * 16 + lc;
            f32x4 hrv = s ? acc1 : acc0;
            f32x4 hzv = s ? acc3 : acc2;
            f32x4 hnv = s ? acc5 : acc4;
            float bh = s ? bh1 : bh0;
#pragma unroll
            for (int r = 0; r < 4; r++) {
                int row = rowg * 4 + r;
                float ir  = bf2f((unsigned short)vir[r * 2 + s]);
                float iz  = bf2f((unsigned short)viz[r * 2 + s]);
                float inn = bf2f((unsigned short)vin[r * 2 + s]);
                float ho  = bf2f(hT[cur][row][j]);
                unsigned short hb = gru_cell(ir, iz, inn, ho, hrv[r], hzv[r], hnv[r], bh);
                yS[cur][row][j] = hb;
                unsigned short hw = hb;
                if (tp + 1 < CHUNK && ((rbr[r] >> (tp + 1)) & 1u)) hw = 0;
                hT[nxt][row][j] = hw;
            }
        }
        __syncthreads();

        // coalesced y store (one 16B full-line write per thread)
        {
            int yrow = tid >> 5, ycol = (tid & 31) * 8;
            short8 yv = *(const short8*)&yS[cur][yrow][ycol];
            *(short8*)(y + ((size_t)t * 256 + b0 + yrow) * 256 + ycol) = yv;
            if (tp == CHUNK - 1)
                *(short8*)(hend + ((size_t)c * 256 + b0 + yrow) * 256 + ycol) = yv;
        }

        vir = nir; viz = niz; vin = nin;
    }
}

// ---------------------------------------------------------------------------
// PARALLEL GRU fixup (verified): 240 WGs = (chunk 1..15) x (16 tiles).
// ---------------------------------------------------------------------------
__global__ __launch_bounds__(512, 1) void k_gru_fix_par(
    const unsigned short* __restrict__ gi, const unsigned short* __restrict__ WhF,
    const int* __restrict__ dones, const float* __restrict__ bhn,
    const unsigned short* __restrict__ hend, unsigned short* __restrict__ y,
    int* __restrict__ flag)
{
    __shared__ unsigned short hT[2][16][264];
    __shared__ unsigned int rowbits[16], prevbits[16];
    __shared__ int sh_fd[16];
    const int tid = threadIdx.x, w = tid >> 6, L = tid & 63;
    const int g = blockIdx.x & 15, c = (blockIdx.x >> 4) + 1;
    const int b0 = g * 16, t0 = c * CHUNK;
    const int rowg = L >> 4, lc = L & 15;
    const int hrow = tid >> 5, hcol = (tid & 31) * 8;

    short8 Bf[6][8];
#pragma unroll
    for (int i6 = 0; i6 < 6; i6++)
#pragma unroll
        for (int ks = 0; ks < 8; ks++)
            Bf[i6][ks] = *(const short8*)(WhF + ((((size_t)w * 6 + i6) * 8 + ks) * 64 + L) * 8);

    const float bh0 = bhn[w * 32 + lc], bh1 = bhn[w * 32 + 16 + lc];

    if (tid < 16) { rowbits[tid] = 0; prevbits[tid] = 0; }
    __syncthreads();
    {
        int tp = tid >> 4, r = tid & 15;
        if (dones[(t0 + tp) * 256 + b0 + r])         atomicOr(&rowbits[r],  1u << tp);
        if (dones[(t0 - CHUNK + tp) * 256 + b0 + r]) atomicOr(&prevbits[r], 1u << tp);
    }
    __syncthreads();
    if (tid < 16) {
        unsigned m = rowbits[tid];
        sh_fd[tid] = m ? __builtin_ctz(m) : CHUNK;
        if (prevbits[tid] == 0) atomicOr(flag, 1);   // carry-in untrusted
    }
    __syncthreads();

    int maxfix = 0;
    unsigned rbr[4]; int fdr[4];
#pragma unroll
    for (int r = 0; r < 16; r++) maxfix = max(maxfix, sh_fd[r]);
    if (maxfix == 0) return;                          // all rows reset at step 0
#pragma unroll
    for (int r = 0; r < 4; r++) {
        rbr[r] = rowbits[rowg * 4 + r];
        fdr[r] = sh_fd[rowg * 4 + r];
    }

    // carry-in: speculative end of chunk c-1, with chunk-c step-0 reset
    {
        short8 hv = *(const short8*)(hend + ((size_t)(c - 1) * 256 + b0 + hrow) * 256 + hcol);
        if (rowbits[hrow] & 1u) { short8 z = {0,0,0,0,0,0,0,0}; hv = z; }
        *(short8*)&hT[0][hrow][hcol] = hv;
    }
    __syncthreads();

    const size_t gstep = (size_t)16 * 512 * 8;
    const size_t gb0 = ((size_t)(t0 * 16 + g) * 512 + tid) * 8;

    int cur = 0;
    for (int tp = 0; tp < maxfix; tp++) {
        const int nxt = cur ^ 1;

        f32x4 acc0 = 0, acc1 = 0, acc2 = 0, acc3 = 0, acc4 = 0, acc5 = 0;
#pragma unroll
        for (int ks = 0; ks < 8; ks++) {
            short8 a = *(const short8*)&hT[cur][lc][ks * 32 + rowg * 8];
            acc0 = __builtin_amdgcn_mfma_f32_16x16x32_bf16(a, Bf[0][ks], acc0, 0, 0, 0);
            acc1 = __builtin_amdgcn_mfma_f32_16x16x32_bf16(a, Bf[1][ks], acc1, 0, 0, 0);
            acc2 = __builtin_amdgcn_mfma_f32_16x16x32_bf16(a, Bf[2][ks], acc2, 0, 0, 0);
            acc3 = __builtin_amdgcn_mfma_f32_16x16x32_bf16(a, Bf[3][ks], acc3, 0, 0, 0);
            acc4 = __builtin_amdgcn_mfma_f32_16x16x32_bf16(a, Bf[4][ks], acc4, 0, 0, 0);
            acc5 = __builtin_amdgcn_mfma_f32_16x16x32_bf16(a, Bf[5][ks], acc5, 0, 0, 0);
        }

        size_t gb = gb0 + (size_t)tp * gstep;
        short8 vir = *(const short8*)(gi + gb);
        short8 viz = *(const short8*)(gi + GIPL + gb);
        short8 vin = *(const short8*)(gi + 2 * GIPL + gb);

        unsigned short* yb = y + (size_t)((t0 + tp) * 256 + b0) * 256;
#pragma unroll
        for (int s = 0; s < 2; s++) {
            const int j = w * 32 + s * 16 + lc;
            f32x4 hrv = s ? acc1 : acc0;
            f32x4 hzv = s ? acc3 : acc2;
            f32x4 hnv = s ? acc5 : acc4;
            float bh = s ? bh1 : bh0;
#pragma unroll
            for (int r = 0; r < 4; r++) {
                int row = rowg * 4 + r;
                float ir  = bf2f((unsigned short)vir[r * 2 + s]);
                float iz  = bf2f((unsigned short)viz[r * 2 + s]);
                float inn = bf2f((unsigned short)vin[r * 2 + s]);
                float ho  = bf2f(hT[cur][row][j]);
                unsigned short hb = gru_cell(ir, iz, inn, ho, hrv[r], hzv[r], hnv[r], bh);
                if (tp < fdr[r]) yb[row * 256 + j] = hb;   // only fix wrong prefix
                unsigned short hw = hb;
                if (tp + 1 < CHUNK && ((rbr[r] >> (tp + 1)) & 1u)) hw = 0;
                hT[nxt][row][j] = hw;
            }
        }
        __syncthreads();
        cur = nxt;
    }
}

// ---------------------------------------------------------------------------
// GRU fixup FALLBACK (sequential over chunks): only runs if flag was set.
// ---------------------------------------------------------------------------
__global__ __launch_bounds__(512, 1) void k_gru_fix(
    const unsigned short* __restrict__ gi, const unsigned short* __restrict__ WhF,
    const int* __restrict__ dones, const float* __restrict__ bhn,
    const unsigned short* __restrict__ hend, unsigned short* __restrict__ y,
    const int* __restrict__ flag)
{
    if (*flag == 0) return;                   // uniform: common case, exit fast

    __shared__ unsigned short hT[2][16][264];
    __shared__ unsigned int rowbits[16];
    __shared__ int sh_fd[16];
    const int tid = threadIdx.x, w = tid >> 6, L = tid & 63;
    const int b0 = blockIdx.x * 16, g = blockIdx.x;
    const int rowg = L >> 4, lc = L & 15;
    const int hrow = tid >> 5, hcol = (tid & 31) * 8;

    short8 Bf[6][8];
#pragma unroll
    for (int i6 = 0; i6 < 6; i6++)
#pragma unroll
        for (int ks = 0; ks < 8; ks++)
            Bf[i6][ks] = *(const short8*)(WhF + ((((size_t)w * 6 + i6) * 8 + ks) * 64 + L) * 8);

    const float bh0 = bhn[w * 32 + lc], bh1 = bhn[w * 32 + 16 + lc];

    // carry = corrected end of chunk 0 (chunk 0 speculation used true h0)
    *(short8*)&hT[0][hrow][hcol] =
        *(const short8*)(hend + (size_t)(b0 + hrow) * 256 + hcol);
    int cur = 0;

    const size_t gstep = (size_t)16 * 512 * 8;

    for (int c = 1; c < NCH; c++) {
        const int t0 = c * CHUNK;
        if (tid < 16) rowbits[tid] = 0;
        __syncthreads();
        {
            int tp = tid >> 4, r = tid & 15;
            if (dones[(t0 + tp) * 256 + b0 + r]) atomicOr(&rowbits[r], 1u << tp);
        }
        __syncthreads();
        if (tid < 16) {
            unsigned m = rowbits[tid];
            sh_fd[tid] = m ? __builtin_ctz(m) : CHUNK;
        }
        __syncthreads();

        int maxfix = 0;
        unsigned rbr[4]; int fdr[4];
#pragma unroll
        for (int r = 0; r < 16; r++) maxfix = max(maxfix, sh_fd[r]);
#pragma unroll
        for (int r = 0; r < 4; r++) {
            rbr[r] = rowbits[rowg * 4 + r];
            fdr[r] = sh_fd[rowg * 4 + r];
        }
        // apply this chunk's step-0 reset to the carry
        if (rowbits[hrow] & 1u) {
#pragma unroll
            for (int cc = 0; cc < 8; cc++) hT[cur][hrow][hcol + cc] = 0;
        }
        __syncthreads();

        const size_t gb0 = ((size_t)(t0 * 16 + g) * 512 + tid) * 8;

        for (int tp = 0; tp < maxfix; tp++) {
            const int nxt = cur ^ 1;

            f32x4 acc0 = 0, acc1 = 0, acc2 = 0, acc3 = 0, acc4 = 0, acc5 = 0;
#pragma unroll
            for (int ks = 0; ks < 8; ks++) {
                short8 a = *(const short8*)&hT[cur][lc][ks * 32 + rowg * 8];
                acc0 = __builtin_amdgcn_mfma_f32_16x16x32_bf16(a, Bf[0][ks], acc0, 0, 0, 0);
                acc1 = __builtin_amdgcn_mfma_f32_16x16x32_bf16(a, Bf[1][ks], acc1, 0, 0, 0);
                acc2 = __builtin_amdgcn_mfma_f32_16x16x32_bf16(a, Bf[2][ks], acc2, 0, 0, 0);
                acc3 = __builtin_amdgcn_mfma_f32_16x16x32_bf16(a, Bf[3][ks], acc3, 0, 0, 0);
                acc4 = __builtin_amdgcn_mfma_f32_16x16x32_bf16(a, Bf[4][ks], acc4, 0, 0, 0);
                acc5 = __builtin_amdgcn_mfma_f32_16x16x32_bf16(a, Bf[5][ks], acc5, 0, 0, 0);
            }

            size_t gb = gb0 + (size_t)tp * gstep;
            short8 vir = *(const short8*)(gi + gb);
            short8 viz = *(const short8*)(gi + GIPL + gb);
            short8 vin = *(const short8*)(gi + 2 * GIPL + gb);

            unsigned short* yb = y + (size_t)((t0 + tp) * 256 + b0) * 256;
#pragma unroll
            for (int s = 0; s < 2; s++) {
                const int j = w * 32 + s * 16 + lc;
                f32x4 hrv = s ? acc1 : acc0;
                f32x4 hzv = s ? acc3 : acc2;
                f32x4 hnv = s ? acc5 : acc4;
                float bh = s ? bh1 : bh0;
#pragma unroll
                for (int r = 0; r < 4; r++) {
                    int row = rowg * 4 + r;
                    float ir  = bf2f((unsigned short)vir[r * 2 + s]);
                    float iz  = bf2f((unsigned short)viz[r * 2 + s]);
                    float inn = bf2f((unsigned short)vin[r * 2 + s]);
                    float ho  = bf2f(hT[cur][row][j]);
                    unsigned short hb = gru_cell(ir, iz, inn, ho, hrv[r], hzv[r], hnv[r], bh);
                    if (tp < fdr[r]) yb[row * 256 + j] = hb;   // only fix wrong prefix
                    unsigned short hw = hb;
                    if (tp + 1 < CHUNK && ((rbr[r] >> (tp + 1)) & 1u)) hw = 0;
                    hT[nxt][row][j] = hw;
                }
            }
            __syncthreads();
            cur = nxt;
        }

        // splice: rows that saw a done have correct speculative h_end
        if (sh_fd[hrow] < CHUNK) {
            *(short8*)&hT[cur][hrow][hcol] =
                *(const short8*)(hend + ((size_t)c * 256 + b0 + hrow) * 256 + hcol);
        }
        __syncthreads();
    }
}

// ---------------------------------------------------------------------------
// G4: logits. As staged (coalesced); WlogF direct (all waves same frag ->
// L2 broadcast). 1024 blocks x 128 rows, 256 threads.
// ---------------------------------------------------------------------------
__global__ __launch_bounds__(256, 2) void k_logits(
    const unsigned short* __restrict__ ac, const unsigned short* __restrict__ WlogF,
    const float* __restrict__ blog,
    const int* __restrict__ av1, const int* __restrict__ av2,
    const int* __restrict__ av3, const int* __restrict__ av4,
    float* __restrict__ outp)
{
    __shared__ unsigned short As[128][72];
    const int tid = threadIdx.x, w = tid >> 6, L = tid & 63;
    const int m0 = blockIdx.x * 128;
    const int sr = tid >> 1, sh = (tid & 1) * 32;
    const int lc = L & 15, lq8 = (L >> 4) * 8, lr = (L >> 4) * 4;

    f32x4 acc[2][10];
#pragma unroll
    for (int i = 0; i < 2; i++)
#pragma unroll
        for (int j = 0; j < 10; j++) acc[i][j] = 0;

    const unsigned short* Ag = ac + (size_t)(m0 + sr) * 512 + sh;

    for (int kt = 0; kt < 256; kt += 64) {
#pragma unroll
        for (int c = 0; c < 32; c += 8)
            *(short8*)&As[sr][sh + c] = *(const short8*)(Ag + kt + c);
        __syncthreads();
#pragma unroll
        for (int ks = 0; ks < 2; ks++) {
            const int kk32 = (kt >> 5) + ks;
            short8 a[2], b[10];
#pragma unroll
            for (int i = 0; i < 2; i++)
                a[i] = *(const short8*)&As[w * 32 + i * 16 + lc][ks * 32 + lq8];
#pragma unroll
            for (int j = 0; j < 10; j++)
                b[j] = *(const short8*)(WlogF + ((((size_t)j * 8 + kk32) * 64 + L) * 8));
#pragma unroll
            for (int i = 0; i < 2; i++)
#pragma unroll
                for (int j = 0; j < 10; j++)
                    acc[i][j] = __builtin_amdgcn_mfma_f32_16x16x32_bf16(a[i], b[j], acc[i][j], 0, 0, 0);
        }
        __syncthreads();
    }
#pragma unroll
    for (int j = 0; j < 10; j++) {
        int col = j * 16 + lc;
        if (col >= 144) continue;
        int gbase, adim; const int* av; size_t obase;
        if      (col < 32) { gbase = 0;  adim = 32; av = av1; obase = OUT_LC1; }
        else if (col < 64) { gbase = 32; adim = 32; av = av2; obase = OUT_LC2; }
        else if (col < 80) { gbase = 64; adim = 16; av = av3; obase = OUT_MC;  }
        else               { gbase = 80; adim = 64; av = av4; obase = OUT_HINT;}
        int cof = col - gbase;
        float bv = blog[col];
#pragma unroll
        for (int i = 0; i < 2; i++)
#pragma unroll
            for (int rg = 0; rg < 4; rg++) {
                int R = m0 + w * 32 + i * 16 + lr + rg;
                float v = acc[i][j][rg] + bv;
                int a_ = av[(size_t)R * adim + cof];
                v -= (1.f - (float)a_) * 1e10f;
                outp[obase + (size_t)R * adim + cof] = v;
            }
    }
}

// ---------------------------------------------------------------------------
// G5: critic (unchanged)
// ---------------------------------------------------------------------------
__global__ __launch_bounds__(256, 4) void k_critic(
    const unsigned short* __restrict__ ac, const float* __restrict__ W_c2,
    const float* __restrict__ b_c2, float* __restrict__ outp)
{
    const int tid = threadIdx.x, w = tid >> 6, L = tid & 63;
    f32x4 wv = *(const f32x4*)(W_c2 + L * 4);
    float bb = b_c2[0];
    int base = blockIdx.x * 64 + w * 16;
    for (int rr = 0; rr < 16; rr++) {
        int R = base + rr;
        const unsigned short* p = ac + (size_t)R * 512 + 256 + L * 4;
        float s = bf2f(p[0]) * wv[0] + bf2f(p[1]) * wv[1] +
                  bf2f(p[2]) * wv[2] + bf2f(p[3]) * wv[3];
#pragma unroll
        for (int o = 32; o > 0; o >>= 1) s += __shfl_down(s, o);
        if (L == 0) outp[OUT_CRIT + R] = s + bb;
    }
}

__global__ __launch_bounds__(256, 4) void k_hidden(
    const unsigned short* __restrict__ y, float* __restrict__ outp)
{
    int i = blockIdx.x * 256 + threadIdx.x;
    outp[OUT_HID + i] = bf2f(y[(size_t)511 * 65536 + i]);
}

// ---------------------------------------------------------------------------
extern "C" void kernel_launch(void* const* d_in, const int* in_sizes, int n_in,
                              void* d_out, int out_size, void* d_ws, size_t ws_size,
                              hipStream_t stream)
{
    const float* hidden = (const float*)d_in[0];
    const float* obs    = (const float*)d_in[1];
    const int*   dones  = (const int*)d_in[2];
    const int*   av1    = (const int*)d_in[3];
    const int*   av2    = (const int*)d_in[4];
    const int*   av3    = (const int*)d_in[5];
    const int*   av4    = (const int*)d_in[6];
    const float* W_emb  = (const float*)d_in[7];
    const float* b_emb  = (const float*)d_in[8];
    const float* Wi     = (const float*)d_in[9];
    const float* bi     = (const float*)d_in[10];
    const float* Wh     = (const float*)d_in[11];
    const float* bhn    = (const float*)d_in[12];
    const float* W_a    = (const float*)d_in[13];
    const float* b_a    = (const float*)d_in[14];
    const float* W_lc1  = (const float*)d_in[15];
    const float* b_lc1  = (const float*)d_in[16];
    const float* W_lc2  = (const float*)d_in[17];
    const float* b_lc2  = (const float*)d_in[18];
    const float* W_mc   = (const float*)d_in[19];
    const float* b_mc   = (const float*)d_in[20];
    const float* W_hint = (const float*)d_in[21];
    const float* b_hint = (const float*)d_in[22];
    const float* W_c1   = (const float*)d_in[23];
    const float* b_c1   = (const float*)d_in[24];
    const float* W_c2   = (const float*)d_in[25];
    const float* b_c2   = (const float*)d_in[26];

    char* ws = (char*)d_ws;
    unsigned short* WembF = (unsigned short*)(ws + 0);
    unsigned short* WiF   = (unsigned short*)(ws + 262144);
    unsigned short* WhF   = (unsigned short*)(ws + 655360);
    unsigned short* WacF  = (unsigned short*)(ws + 1048576);
    unsigned short* WlogF = (unsigned short*)(ws + 1310720);
    float*          blog  = (float*)(ws + 1392640);
    int*            fflag = (int*)(ws + 1393280);
    // hend (2 MB) / ac (134 MB) share a region. hend lives gru_main->gru_fix;
    // ac written by G3 after fixup.
    unsigned short* hend  = (unsigned short*)(ws + 1393664);
    unsigned short* ac    = hend;
    unsigned short* gibuf = (unsigned short*)(ws + 135611392);
    unsigned short* ybuf  = (unsigned short*)(ws + 336937984);
    float* outp = (float*)d_out;

    k_prep<<<2721, 256, 0, stream>>>(W_emb, Wi, Wh, W_a, W_c1, W_lc1, W_lc2,
                                     W_mc, W_hint, b_lc1, b_lc2, b_mc, b_hint,
                                     WembF, WiF, WhF, WacF, WlogF, blog, fflag);
    k_fused_g12<<<2048, 512, 0, stream>>>(obs, WembF, b_emb, WiF, bi, gibuf);
    k_gru_main<<<256, 512, 0, stream>>>(gibuf, WhF, dones, hidden, bhn, ybuf, hend);
    k_gru_fix_par<<<240, 512, 0, stream>>>(gibuf, WhF, dones, bhn, hend, ybuf, fflag);
    k_gru_fix<<<16, 512, 0, stream>>>(gibuf, WhF, dones, bhn, hend, ybuf, fflag);
    k_gemm_ac<<<2048, 512, 0, stream>>>(ybuf, WacF, b_a, b_c1, ac);
    k_logits<<<1024, 256, 0, stream>>>(ac, WlogF, blog, av1, av2, av3, av4, outp);
    k_critic<<<2048, 256, 0, stream>>>(ac, W_c2, b_c2, outp);
    k_hidden<<<2048 / 8, 256, 0, stream>>>(ybuf, outp);
}

// Round 6
// 858.380 us; speedup vs baseline: 1.4590x; 1.0177x over previous
//
#include <hip/hip_runtime.h>
#include <stdint.h>

// ---------------------------------------------------------------------------
// ActorCriticRNN on MI355X.
//   prep:  weights -> bf16 FRAGMENT-LINEAR layouts (WembF/WiF/WacF/WlogF/WhF):
//          each MFMA B-fragment is 64 lanes x 16B contiguous -> one 1KB burst,
//          L2-resident. (R4 lesson: direct frag loads from row-major B touch
//          16 segments/instr and become request-rate bound.)
//   G12:   FUSED: phase 1 emb = relu(obs @ W_emb + b), As DOUBLE-BUFFERED
//          (1 barrier/kt, loads overlap MFMA), B direct from WembF.
//          phase 2: gi = eS @ WiF + bi, ZERO barriers, packed gate-plane out.
//   GRU:   chunk-parallel speculation (verified R2/R3 version).
//   HEAD:  k_head fuses G3+G4+G5+hidden: ac never hits HBM (saves 335 MB).
//          yS staged once -> [a|c] GEMM (WacF direct) -> a->aS, c->yS(reuse)
//          -> logits (aS + WlogF) + critic (shuffle-reduce on cS) + hidden.
// ---------------------------------------------------------------------------

typedef short short8 __attribute__((ext_vector_type(8)));
typedef float f32x4  __attribute__((ext_vector_type(4)));

#define T_DIM 512
#define CHUNK 32
#define NCH   16
#define GIPL  ((size_t)33554432)   // gi gate-plane size in shorts (8192*512*8)

// output offsets (fp32 elements)
#define OUT_HID  ((size_t)0)
#define OUT_LC1  ((size_t)65536)
#define OUT_LC2  ((size_t)4259840)
#define OUT_MC   ((size_t)8454144)
#define OUT_HINT ((size_t)10551296)
#define OUT_CRIT ((size_t)18939904)

__device__ __forceinline__ unsigned short f2bf(float f) {
    unsigned u = __float_as_uint(f);
    u += 0x7fffu + ((u >> 16) & 1u);          // round-to-nearest-even
    return (unsigned short)(u >> 16);
}
__device__ __forceinline__ float bf2f(unsigned short h) {
    return __uint_as_float(((unsigned)h) << 16);
}

__device__ __forceinline__ unsigned short gru_cell(
    float ir, float iz, float inn, float ho,
    float hrv, float hzv, float hnv, float bh)
{
    float rg = 1.f / (1.f + __expf(-(ir + hrv)));
    float z  = 1.f / (1.f + __expf(-(iz + hzv)));
    float ex = __expf(2.f * (inn + rg * (hnv + bh)));
    float n  = 1.f - 2.f / (ex + 1.f);        // tanh, inf-safe
    return f2bf((1.f - z) * n + z * ho);
}

// ---------------------------------------------------------------------------
// prep: all weights to fragment-linear bf16 (verified R5).
// Fragment element convention (matches in-kernel MFMA usage everywhere):
//   lane L, elem jj ->  n = nbase + (L&15),  k = kbase + ((L>>4)<<3) + jj
// ---------------------------------------------------------------------------
__global__ __launch_bounds__(256, 4) void k_prep(
    const float* __restrict__ W_emb, const float* __restrict__ Wi,
    const float* __restrict__ Wh,    const float* __restrict__ W_a,
    const float* __restrict__ W_c1,  const float* __restrict__ W_lc1,
    const float* __restrict__ W_lc2, const float* __restrict__ W_mc,
    const float* __restrict__ W_hint,
    const float* __restrict__ b_lc1, const float* __restrict__ b_lc2,
    const float* __restrict__ b_mc,  const float* __restrict__ b_hint,
    unsigned short* __restrict__ WembF, unsigned short* __restrict__ WiF,
    unsigned short* __restrict__ WhF,   unsigned short* __restrict__ WacF,
    unsigned short* __restrict__ WlogF, float* __restrict__ blog,
    int* __restrict__ fixflag)
{
    int i = blockIdx.x * 256 + threadIdx.x;
    if (i < 131072) {                         // WembF: frag (q, j, kt32)
        int jj = i & 7, L = (i >> 3) & 63, kt32 = (i >> 9) & 15;
        int j = (i >> 13) & 3, q = (i >> 15) & 3;
        int n = q * 64 + j * 16 + (L & 15);
        int k = kt32 * 32 + ((L >> 4) << 3) + jj;
        WembF[i] = f2bf(W_emb[k * 256 + n]);
        return;
    }
    i -= 131072;
    if (i < 196608) {                         // WiF: frag (nc, q, j, kk32)
        int jj = i & 7, L = (i >> 3) & 63, kk32 = (i >> 9) & 7;
        int j = (i >> 12) & 3, q = (i >> 14) & 3, nc = i >> 16;
        int n = nc * 256 + q * 64 + j * 16 + (L & 15);
        int k = kk32 * 32 + ((L >> 4) << 3) + jj;
        WiF[i] = f2bf(Wi[k * 768 + n]);
        return;
    }
    i -= 196608;
    if (i < 196608) {                         // Wh fragment-linear (GRU, verified)
        int jj = i & 7, L = (i >> 3) & 63, ks = (i >> 9) & 7, rest = i >> 12;
        int w = rest / 6, i6 = rest % 6, rho = i6 >> 1, s = i6 & 1;
        int k   = ks * 32 + ((L >> 4) << 3) + jj;
        int col = rho * 256 + w * 32 + s * 16 + (L & 15);
        WhF[i] = f2bf(Wh[k * 768 + col]);
        return;
    }
    i -= 196608;
    if (i < 131072) {                         // WacF: frag (nc, q, j, kk32)
        int jj = i & 7, L = (i >> 3) & 63, kk32 = (i >> 9) & 7;
        int j = (i >> 12) & 3, q = (i >> 14) & 3, nc = (i >> 16) & 1;
        int n = nc * 256 + q * 64 + j * 16 + (L & 15);
        int k = kk32 * 32 + ((L >> 4) << 3) + jj;
        WacF[i] = f2bf(n < 256 ? W_a[k * 256 + n] : W_c1[k * 256 + (n - 256)]);
        return;
    }
    i -= 131072;
    if (i < 40960) {                          // WlogF: frag (j, kk32), N pad 160
        int jj = i & 7, L = (i >> 3) & 63, kk32 = (i >> 9) & 7;
        int j = i >> 12;                      // 0..9
        int n = j * 16 + (L & 15);
        int k = kk32 * 32 + ((L >> 4) << 3) + jj;
        float v;
        if      (n < 32)  v = W_lc1[k * 32 + n];
        else if (n < 64)  v = W_lc2[k * 32 + (n - 32)];
        else if (n < 80)  v = W_mc [k * 16 + (n - 64)];
        else if (n < 144) v = W_hint[k * 64 + (n - 80)];
        else              v = 0.f;
        WlogF[i] = f2bf(v);
        return;
    }
    i -= 40960;
    if (i < 160) {
        float v;
        if      (i < 32)  v = b_lc1[i];
        else if (i < 64)  v = b_lc2[i - 32];
        else if (i < 80)  v = b_mc [i - 64];
        else if (i < 144) v = b_hint[i - 80];
        else              v = 0.f;
        blog[i] = v;
        return;
    }
    i -= 160;
    if (i == 0) *fixflag = 0;
}

// ---------------------------------------------------------------------------
// FUSED G1+G2. 2048 blocks x 64 rows, 512 threads = 8 waves (2m x 4n).
//   phase 1: As double-buffered (1 barrier/kt; obs loads overlap MFMA),
//            B-frags direct from WembF. relu+bias -> eS. 1 barrier.
//   phase 2: 3 gate chunks, a from eS (LDS), b direct from WiF. ZERO barriers.
// ---------------------------------------------------------------------------
__global__ __launch_bounds__(512, 3) void k_fused_g12(
    const float* __restrict__ obs, const unsigned short* __restrict__ WembF,
    const float* __restrict__ b_emb, const unsigned short* __restrict__ WiF,
    const float* __restrict__ bi, unsigned short* __restrict__ out)
{
    __shared__ unsigned short As[2][64][72];
    __shared__ unsigned short eS[64][264];
    const int tid = threadIdx.x, w = tid >> 6, L = tid & 63;
    const int mq = (w >> 2) * 32, wq = w & 3, nq = wq * 64;
    const int m0 = blockIdx.x * 64;
    const int lc = L & 15, lq8 = (L >> 4) * 8, lr = (L >> 4) * 4;
    const int sra = tid >> 3, sha = (tid & 7) * 8;   // As staging: 8 thr/row

    const float* Ag = obs + (size_t)(m0 + sra) * 512 + sha;

    auto stage_a = [&](int kt, int p) {
        f32x4 v0 = *(const f32x4*)(Ag + kt);
        f32x4 v1 = *(const f32x4*)(Ag + kt + 4);
        short8 pk;
        pk[0] = (short)f2bf(v0[0]); pk[1] = (short)f2bf(v0[1]);
        pk[2] = (short)f2bf(v0[2]); pk[3] = (short)f2bf(v0[3]);
        pk[4] = (short)f2bf(v1[0]); pk[5] = (short)f2bf(v1[1]);
        pk[6] = (short)f2bf(v1[2]); pk[7] = (short)f2bf(v1[3]);
        *(short8*)&As[p][sra][sha] = pk;
    };

    f32x4 acc[2][4];
#pragma unroll
    for (int i = 0; i < 2; i++)
#pragma unroll
        for (int j = 0; j < 4; j++) acc[i][j] = 0;

    // ---- phase 1: acc = obs @ WembF, double-buffered As ----
    stage_a(0, 0);
    __syncthreads();
    int p = 0;
    for (int kt = 0; kt < 512; kt += 64) {
        if (kt + 64 < 512) stage_a(kt + 64, p ^ 1);
#pragma unroll
        for (int ks = 0; ks < 2; ks++) {
            const int kt32 = (kt >> 5) + ks;
            short8 a[2], b[4];
#pragma unroll
            for (int i = 0; i < 2; i++)
                a[i] = *(const short8*)&As[p][mq + i * 16 + lc][ks * 32 + lq8];
#pragma unroll
            for (int j = 0; j < 4; j++)
                b[j] = *(const short8*)(WembF +
                        ((((size_t)(wq * 4 + j) * 16 + kt32) * 64 + L) * 8));
#pragma unroll
            for (int i = 0; i < 2; i++)
#pragma unroll
                for (int j = 0; j < 4; j++)
                    acc[i][j] = __builtin_amdgcn_mfma_f32_16x16x32_bf16(a[i], b[j], acc[i][j], 0, 0, 0);
        }
        __syncthreads();
        p ^= 1;
    }
    // epilogue phase 1: relu -> bf16 -> eS
#pragma unroll
    for (int i = 0; i < 2; i++)
#pragma unroll
        for (int j = 0; j < 4; j++) {
            int col = nq + j * 16 + lc;
            float bv = b_emb[col];
#pragma unroll
            for (int rg = 0; rg < 4; rg++) {
                int row = mq + i * 16 + lr + rg;
                eS[row][col] = f2bf(fmaxf(acc[i][j][rg] + bv, 0.f));
            }
        }
    __syncthreads();

    // ---- phase 2: gi = eS @ WiF + bi, 3 gate chunks, no barriers ----
    for (int nc = 0; nc < 3; nc++) {
#pragma unroll
        for (int i = 0; i < 2; i++)
#pragma unroll
            for (int j = 0; j < 4; j++) acc[i][j] = 0;

#pragma unroll 2
        for (int kk = 0; kk < 256; kk += 32) {
            const int kk32 = kk >> 5;
            short8 a[2], b[4];
#pragma unroll
            for (int i = 0; i < 2; i++)
                a[i] = *(const short8*)&eS[mq + i * 16 + lc][kk + lq8];
#pragma unroll
            for (int j = 0; j < 4; j++)
                b[j] = *(const short8*)(WiF +
                        ((((size_t)((nc * 4 + wq) * 4 + j) * 8 + kk32) * 64 + L) * 8));
#pragma unroll
            for (int i = 0; i < 2; i++)
#pragma unroll
                for (int j = 0; j < 4; j++)
                    acc[i][j] = __builtin_amdgcn_mfma_f32_16x16x32_bf16(a[i], b[j], acc[i][j], 0, 0, 0);
        }
        // packed epilogue (verified formulas)
#pragma unroll
        for (int i = 0; i < 2; i++) {
            const int row0  = m0 + mq + i * 16 + lr;
            const int t     = row0 >> 8;
            const int g     = (row0 >> 4) & 15;
            const int rowg2 = (row0 >> 2) & 3;
#pragma unroll
            for (int jh = 0; jh < 2; jh++) {
                const int colb = nc * 256 + nq + jh * 32;
                const int gate = colb >> 8;
                const int w2   = (colb & 255) >> 5;
                short8 pk;
#pragma unroll
                for (int rg = 0; rg < 4; rg++)
#pragma unroll
                    for (int s = 0; s < 2; s++) {
                        int col = colb + s * 16 + lc;
                        float v = acc[i][jh * 2 + s][rg] + bi[col];
                        pk[rg * 2 + s] = (short)f2bf(v);
                    }
                size_t dst = (size_t)gate * GIPL +
                             (((size_t)(t * 16 + g) * 512) + (size_t)w2 * 64 +
                              (size_t)rowg2 * 16 + lc) * 8;
                *(short8*)(out + dst) = pk;
            }
        }
    }
}

// ---------------------------------------------------------------------------
// HEAD: fused G3 + logits + critic + hidden. 2048 blocks x 64 rows, 512 thr.
//   stage yS -> [a|c] GEMM (WacF direct, no inner barriers) -> barrier ->
//   a->aS, c->yS (yS dead after GEMM) -> barrier ->
//   logits (A from aS, B WlogF; wave = (mf = w>>1, jh = (w&1)*5)) +
//   critic (per-row dot of cS with W_c2, wave shuffle-reduce) +
//   hidden (last-timestep blocks copy yS before overwrite).
// ac NEVER touches HBM (saves 335 MB of intermediate traffic).
// ---------------------------------------------------------------------------
__global__ __launch_bounds__(512, 2) void k_head(
    const unsigned short* __restrict__ y, const unsigned short* __restrict__ WacF,
    const float* __restrict__ b_a, const float* __restrict__ b_c1,
    const unsigned short* __restrict__ WlogF, const float* __restrict__ blog,
    const float* __restrict__ W_c2, const float* __restrict__ b_c2,
    const int* __restrict__ av1, const int* __restrict__ av2,
    const int* __restrict__ av3, const int* __restrict__ av4,
    float* __restrict__ outp)
{
    __shared__ unsigned short yS[64][264];   // reused as cS after the GEMM
    __shared__ unsigned short aS[64][264];
    const int tid = threadIdx.x, w = tid >> 6, L = tid & 63;
    const int mq = (w >> 2) * 32, wq = w & 3, nq = wq * 64;
    const int m0 = blockIdx.x * 64;
    const int lc = L & 15, lq8 = (L >> 4) * 8, lr = (L >> 4) * 4;

    // stage y tile once: 32 shorts/thread, coalesced
    {
        int r = tid >> 3, cb = (tid & 7) * 32;
        const unsigned short* yg = y + (size_t)(m0 + r) * 256 + cb;
#pragma unroll
        for (int c = 0; c < 32; c += 8)
            *(short8*)&yS[r][cb + c] = *(const short8*)(yg + c);
    }
    __syncthreads();

    // hidden output: rows of t = 511 live in blocks with m0 >= 130816
    if (m0 >= 130816) {
        int r = tid >> 3, cb = (tid & 7) * 32;
        int b = (m0 - 130816) + r;
#pragma unroll
        for (int c = 0; c < 32; c++)
            outp[OUT_HID + (size_t)b * 256 + cb + c] = bf2f(yS[r][cb + c]);
    }

    // ---- [a|c] GEMM: acc from yS (LDS) x WacF (direct), no barriers ----
    f32x4 accA[2][4], accC[2][4];
#pragma unroll
    for (int i = 0; i < 2; i++)
#pragma unroll
        for (int j = 0; j < 4; j++) { accA[i][j] = 0; accC[i][j] = 0; }

#pragma unroll 2
    for (int kk32 = 0; kk32 < 8; kk32++) {
        short8 a[2], bA[4], bC[4];
#pragma unroll
        for (int i = 0; i < 2; i++)
            a[i] = *(const short8*)&yS[mq + i * 16 + lc][kk32 * 32 + lq8];
#pragma unroll
        for (int j = 0; j < 4; j++) {
            bA[j] = *(const short8*)(WacF +
                    ((((size_t)(wq * 4 + j) * 8 + kk32) * 64 + L) * 8));
            bC[j] = *(const short8*)(WacF +
                    ((((size_t)((4 + wq) * 4 + j) * 8 + kk32) * 64 + L) * 8));
        }
#pragma unroll
        for (int i = 0; i < 2; i++)
#pragma unroll
            for (int j = 0; j < 4; j++) {
                accA[i][j] = __builtin_amdgcn_mfma_f32_16x16x32_bf16(a[i], bA[j], accA[i][j], 0, 0, 0);
                accC[i][j] = __builtin_amdgcn_mfma_f32_16x16x32_bf16(a[i], bC[j], accC[i][j], 0, 0, 0);
            }
    }
    __syncthreads();   // all yS reads done; safe to overwrite

    // write a -> aS, c -> yS (cS); bf16 rounding identical to old path
#pragma unroll
    for (int i = 0; i < 2; i++)
#pragma unroll
        for (int j = 0; j < 4; j++) {
            int col = nq + j * 16 + lc;
            float bvA = b_a[col], bvC = b_c1[col];
#pragma unroll
            for (int rg = 0; rg < 4; rg++) {
                int row = mq + i * 16 + lr + rg;
                aS[row][col] = f2bf(fmaxf(accA[i][j][rg] + bvA, 0.f));
                yS[row][col] = f2bf(fmaxf(accC[i][j][rg] + bvC, 0.f));
            }
        }
    __syncthreads();

    // ---- logits: A from aS, B from WlogF; wave: mf = w>>1, jh = (w&1)*5 ----
    {
        const int mf = w >> 1, jh = (w & 1) * 5;
        f32x4 accL[5];
#pragma unroll
        for (int j5 = 0; j5 < 5; j5++) accL[j5] = 0;

#pragma unroll 2
        for (int kk32 = 0; kk32 < 8; kk32++) {
            short8 a = *(const short8*)&aS[mf * 16 + lc][kk32 * 32 + lq8];
#pragma unroll
            for (int j5 = 0; j5 < 5; j5++) {
                short8 b = *(const short8*)(WlogF +
                        ((((size_t)(jh + j5) * 8 + kk32) * 64 + L) * 8));
                accL[j5] = __builtin_amdgcn_mfma_f32_16x16x32_bf16(a, b, accL[j5], 0, 0, 0);
            }
        }
#pragma unroll
        for (int j5 = 0; j5 < 5; j5++) {
            int col = (jh + j5) * 16 + lc;
            if (col >= 144) continue;
            int gbase, adim; const int* av; size_t obase;
            if      (col < 32) { gbase = 0;  adim = 32; av = av1; obase = OUT_LC1; }
            else if (col < 64) { gbase = 32; adim = 32; av = av2; obase = OUT_LC2; }
            else if (col < 80) { gbase = 64; adim = 16; av = av3; obase = OUT_MC;  }
            else               { gbase = 80; adim = 64; av = av4; obase = OUT_HINT;}
            int cof = col - gbase;
            float bv = blog[col];
#pragma unroll
            for (int rg = 0; rg < 4; rg++) {
                int R = m0 + mf * 16 + lr + rg;
                float v = accL[j5][rg] + bv;
                int a_ = av[(size_t)R * adim + cof];
                v -= (1.f - (float)a_) * 1e10f;
                outp[obase + (size_t)R * adim + cof] = v;
            }
        }
    }

    // ---- critic: per-row dot of cS (=yS) with W_c2, 8 rows per wave ----
    {
        f32x4 wv = *(const f32x4*)(W_c2 + L * 4);
        float bb = b_c2[0];
#pragma unroll
        for (int rr = 0; rr < 8; rr++) {
            int row = w * 8 + rr;
            const unsigned short* pc = &yS[row][L * 4];
            float s = bf2f(pc[0]) * wv[0] + bf2f(pc[1]) * wv[1] +
                      bf2f(pc[2]) * wv[2] + bf2f(pc[3]) * wv[3];
#pragma unroll
            for (int o = 32; o > 0; o >>= 1) s += __shfl_down(s, o);
            if (L == 0) outp[OUT_CRIT + m0 + row] = s + bb;
        }
    }
}

// ---------------------------------------------------------------------------
// GRU main pass (verified R2/R3 version)
// ---------------------------------------------------------------------------
__global__ __launch_bounds__(512, 1) void k_gru_main(
    const unsigned short* __restrict__ gi, const unsigned short* __restrict__ WhF,
    const int* __restrict__ dones, const float* __restrict__ h0,
    const float* __restrict__ bhn, unsigned short* __restrict__ y,
    unsigned short* __restrict__ hend)
{
    __shared__ unsigned short hT[2][16][264];
    __shared__ unsigned short yS[2][16][256];
    __shared__ unsigned int rowbits[16];      // bit t' of dones for each row
    const int tid = threadIdx.x, w = tid >> 6, L = tid & 63;
    const int g = blockIdx.x & 15, c = blockIdx.x >> 4;
    const int b0 = g * 16, t0 = c * CHUNK;
    const int rowg = L >> 4, lc = L & 15;

    short8 Bf[6][8];
#pragma unroll
    for (int i6 = 0; i6 < 6; i6++)
#pragma unroll
        for (int ks = 0; ks < 8; ks++)
            Bf[i6][ks] = *(const short8*)(WhF + ((((size_t)w * 6 + i6) * 8 + ks) * 64 + L) * 8);

    const float bh0 = bhn[w * 32 + lc], bh1 = bhn[w * 32 + 16 + lc];

    // build dones bitmask for this chunk
    if (tid < 16) rowbits[tid] = 0;
    __syncthreads();
    {
        int tp = tid >> 4, r = tid & 15;
        if (dones[(t0 + tp) * 256 + b0 + r]) atomicOr(&rowbits[r], 1u << tp);
    }
    __syncthreads();

    unsigned rbr[4];
#pragma unroll
    for (int r = 0; r < 4; r++) rbr[r] = rowbits[rowg * 4 + r];

    // init h: c==0 -> h0 with done[0] reset; c>0 -> speculative 0
    {
        int hrow = tid >> 5, hcol = (tid & 31) * 8;
        bool rz = (rowbits[hrow] & 1u) != 0;
#pragma unroll
        for (int cc = 0; cc < 8; cc++) {
            unsigned short v = 0;
            if (c == 0 && !rz) v = f2bf(h0[(b0 + hrow) * 256 + hcol + cc]);
            hT[0][hrow][hcol + cc] = v;
        }
    }
    __syncthreads();

    // gi packed base for this thread: ((t*16+g)*512 + tid)*8, t = t0+tp
    const size_t gstep = (size_t)16 * 512 * 8;
    size_t gb = ((size_t)(t0 * 16 + g) * 512 + tid) * 8;
    short8 vir = *(const short8*)(gi + gb);
    short8 viz = *(const short8*)(gi + GIPL + gb);
    short8 vin = *(const short8*)(gi + 2 * GIPL + gb);

#pragma unroll 2
    for (int tp = 0; tp < CHUNK; tp++) {
        const int cur = tp & 1, nxt = cur ^ 1;
        const int t = t0 + tp;

        // prefetch next step's gi (independent of h)
        short8 nir, niz, nin;
        if (tp + 1 < CHUNK) {
            size_t gn = gb + (size_t)(tp + 1) * gstep;
            nir = *(const short8*)(gi + gn);
            niz = *(const short8*)(gi + GIPL + gn);
            nin = *(const short8*)(gi + 2 * GIPL + gn);
        }

        f32x4 acc0 = 0, acc1 = 0, acc2 = 0, acc3 = 0, acc4 = 0, acc5 = 0;
#pragma unroll
        for (int ks = 0; ks < 8; ks++) {
            short8 a = *(const short8*)&hT[cur][lc][ks * 32 + rowg * 8];
            acc0 = __builtin_amdgcn_mfma_f32_16x16x32_bf16(a, Bf[0][ks], acc0, 0, 0, 0);
            acc1 = __builtin_amdgcn_mfma_f32_16x16x32_bf16(a, Bf[1][ks], acc1, 0, 0, 0);
            acc2 = __builtin_amdgcn_mfma_f32_16x16x32_bf16(a, Bf[2][ks], acc2, 0, 0, 0);
            acc3 = __builtin_amdgcn_mfma_f32_16x16x32_bf16(a, Bf[3][ks], acc3, 0, 0, 0);
            acc4 = __builtin_amdgcn_mfma_f32_16x16x32_bf16(a, Bf[4][ks], acc4, 0, 0, 0);
            acc5 = __builtin_amdgcn_mfma_f32_16x16x32_bf16(a, Bf[5][ks], acc5, 0, 0, 0);
        }

#pragma unroll
        for (int s = 0; s < 2; s++) {
            const int j = w * 32 + s * 16 + lc;
            f32x4 hrv = s ? acc1 : acc0;
            f32x4 hzv = s ? acc3 : acc2;
            f32x4 hnv = s ? acc5 : acc4;
            float bh = s ? bh1 : bh0;
#pragma unroll
            for (int r = 0; r < 4; r++) {
                int row = rowg * 4 + r;
                float ir  = bf2f((unsigned short)vir[r * 2 + s]);
                float iz  = bf2f((unsigned short)viz[r * 2 + s]);
                float inn = bf2f((unsigned short)vin[r * 2 + s]);
                float ho  = bf2f(hT[cur][row][j]);
                unsigned short hb = gru_cell(ir, iz, inn, ho, hrv[r], hzv[r], hnv[r], bh);
                yS[cur][row][j] = hb;
                unsigned short hw = hb;
                if (tp + 1 < CHUNK && ((rbr[r] >> (tp + 1)) & 1u)) hw = 0;
                hT[nxt][row][j] = hw;
            }
        }
        __syncthreads();

        // coalesced y store (one 16B full-line write per thread)
        {
            int yrow = tid >> 5, ycol = (tid & 31) * 8;
            short8 yv = *(const short8*)&yS[cur][yrow][ycol];
            *(short8*)(y + ((size_t)t * 256 + b0 + yrow) * 256 + ycol) = yv;
            if (tp == CHUNK - 1)
                *(short8*)(hend + ((size_t)c * 256 + b0 + yrow) * 256 + ycol) = yv;
        }

        vir = nir; viz = niz; vin = nin;
    }
}

// ---------------------------------------------------------------------------
// PARALLEL GRU fixup (verified): 240 WGs = (chunk 1..15) x (16 tiles).
// ---------------------------------------------------------------------------
__global__ __launch_bounds__(512, 1) void k_gru_fix_par(
    const unsigned short* __restrict__ gi, const unsigned short* __restrict__ WhF,
    const int* __restrict__ dones, const float* __restrict__ bhn,
    const unsigned short* __restrict__ hend, unsigned short* __restrict__ y,
    int* __restrict__ flag)
{
    __shared__ unsigned short hT[2][16][264];
    __shared__ unsigned int rowbits[16], prevbits[16];
    __shared__ int sh_fd[16];
    const int tid = threadIdx.x, w = tid >> 6, L = tid & 63;
    const int g = blockIdx.x & 15, c = (blockIdx.x >> 4) + 1;
    const int b0 = g * 16, t0 = c * CHUNK;
    const int rowg = L >> 4, lc = L & 15;
    const int hrow = tid >> 5, hcol = (tid & 31) * 8;

    short8 Bf[6][8];
#pragma unroll
    for (int i6 = 0; i6 < 6; i6++)
#pragma unroll
        for (int ks = 0; ks < 8; ks++)
            Bf[i6][ks] = *(const short8*)(WhF + ((((size_t)w * 6 + i6) * 8 + ks) * 64 + L) * 8);

    const float bh0 = bhn[w * 32 + lc], bh1 = bhn[w * 32 + 16 + lc];

    if (tid < 16) { rowbits[tid] = 0; prevbits[tid] = 0; }
    __syncthreads();
    {
        int tp = tid >> 4, r = tid & 15;
        if (dones[(t0 + tp) * 256 + b0 + r])         atomicOr(&rowbits[r],  1u << tp);
        if (dones[(t0 - CHUNK + tp) * 256 + b0 + r]) atomicOr(&prevbits[r], 1u << tp);
    }
    __syncthreads();
    if (tid < 16) {
        unsigned m = rowbits[tid];
        sh_fd[tid] = m ? __builtin_ctz(m) : CHUNK;
        if (prevbits[tid] == 0) atomicOr(flag, 1);   // carry-in untrusted
    }
    __syncthreads();

    int maxfix = 0;
    unsigned rbr[4]; int fdr[4];
#pragma unroll
    for (int r = 0; r < 16; r++) maxfix = max(maxfix, sh_fd[r]);
    if (maxfix == 0) return;                          // all rows reset at step 0
#pragma unroll
    for (int r = 0; r < 4; r++) {
        rbr[r] = rowbits[rowg * 4 + r];
        fdr[r] = sh_fd[rowg * 4 + r];
    }

    // carry-in: speculative end of chunk c-1, with chunk-c step-0 reset
    {
        short8 hv = *(const short8*)(hend + ((size_t)(c - 1) * 256 + b0 + hrow) * 256 + hcol);
        if (rowbits[hrow] & 1u) { short8 z = {0,0,0,0,0,0,0,0}; hv = z; }
        *(short8*)&hT[0][hrow][hcol] = hv;
    }
    __syncthreads();

    const size_t gstep = (size_t)16 * 512 * 8;
    const size_t gb0 = ((size_t)(t0 * 16 + g) * 512 + tid) * 8;

    int cur = 0;
    for (int tp = 0; tp < maxfix; tp++) {
        const int nxt = cur ^ 1;

        f32x4 acc0 = 0, acc1 = 0, acc2 = 0, acc3 = 0, acc4 = 0, acc5 = 0;
#pragma unroll
        for (int ks = 0; ks < 8; ks++) {
            short8 a = *(const short8*)&hT[cur][lc][ks * 32 + rowg * 8];
            acc0 = __builtin_amdgcn_mfma_f32_16x16x32_bf16(a, Bf[0][ks], acc0, 0, 0, 0);
            acc1 = __builtin_amdgcn_mfma_f32_16x16x32_bf16(a, Bf[1][ks], acc1, 0, 0, 0);
            acc2 = __builtin_amdgcn_mfma_f32_16x16x32_bf16(a, Bf[2][ks], acc2, 0, 0, 0);
            acc3 = __builtin_amdgcn_mfma_f32_16x16x32_bf16(a, Bf[3][ks], acc3, 0, 0, 0);
            acc4 = __builtin_amdgcn_mfma_f32_16x16x32_bf16(a, Bf[4][ks], acc4, 0, 0, 0);
            acc5 = __builtin_amdgcn_mfma_f32_16x16x32_bf16(a, Bf[5][ks], acc5, 0, 0, 0);
        }

        size_t gb = gb0 + (size_t)tp * gstep;
        short8 vir = *(const short8*)(gi + gb);
        short8 viz = *(const short8*)(gi + GIPL + gb);
        short8 vin = *(const short8*)(gi + 2 * GIPL + gb);

        unsigned short* yb = y + (size_t)((t0 + tp) * 256 + b0) * 256;
#pragma unroll
        for (int s = 0; s < 2; s++) {
            const int j = w * 32 + s * 16 + lc;
            f32x4 hrv = s ? acc1 : acc0;
            f32x4 hzv = s ? acc3 : acc2;
            f32x4 hnv = s ? acc5 : acc4;
            float bh = s ? bh1 : bh0;
#pragma unroll
            for (int r = 0; r < 4; r++) {
                int row = rowg * 4 + r;
                float ir  = bf2f((unsigned short)vir[r * 2 + s]);
                float iz  = bf2f((unsigned short)viz[r * 2 + s]);
                float inn = bf2f((unsigned short)vin[r * 2 + s]);
                float ho  = bf2f(hT[cur][row][j]);
                unsigned short hb = gru_cell(ir, iz, inn, ho, hrv[r], hzv[r], hnv[r], bh);
                if (tp < fdr[r]) yb[row * 256 + j] = hb;   // only fix wrong prefix
                unsigned short hw = hb;
                if (tp + 1 < CHUNK && ((rbr[r] >> (tp + 1)) & 1u)) hw = 0;
                hT[nxt][row][j] = hw;
            }
        }
        __syncthreads();
        cur = nxt;
    }
}

// ---------------------------------------------------------------------------
// GRU fixup FALLBACK (sequential over chunks): only runs if flag was set.
// ---------------------------------------------------------------------------
__global__ __launch_bounds__(512, 1) void k_gru_fix(
    const unsigned short* __restrict__ gi, const unsigned short* __restrict__ WhF,
    const int* __restrict__ dones, const float* __restrict__ bhn,
    const unsigned short* __restrict__ hend, unsigned short* __restrict__ y,
    const int* __restrict__ flag)
{
    if (*flag == 0) return;                   // uniform: common case, exit fast

    __shared__ unsigned short hT[2][16][264];
    __shared__ unsigned int rowbits[16];
    __shared__ int sh_fd[16];
    const int tid = threadIdx.x, w = tid >> 6, L = tid & 63;
    const int b0 = blockIdx.x * 16, g = blockIdx.x;
    const int rowg = L >> 4, lc = L & 15;
    const int hrow = tid >> 5, hcol = (tid & 31) * 8;

    short8 Bf[6][8];
#pragma unroll
    for (int i6 = 0; i6 < 6; i6++)
#pragma unroll
        for (int ks = 0; ks < 8; ks++)
            Bf[i6][ks] = *(const short8*)(WhF + ((((size_t)w * 6 + i6) * 8 + ks) * 64 + L) * 8);

    const float bh0 = bhn[w * 32 + lc], bh1 = bhn[w * 32 + 16 + lc];

    // carry = corrected end of chunk 0 (chunk 0 speculation used true h0)
    *(short8*)&hT[0][hrow][hcol] =
        *(const short8*)(hend + (size_t)(b0 + hrow) * 256 + hcol);
    int cur = 0;

    const size_t gstep = (size_t)16 * 512 * 8;

    for (int c = 1; c < NCH; c++) {
        const int t0 = c * CHUNK;
        if (tid < 16) rowbits[tid] = 0;
        __syncthreads();
        {
            int tp = tid >> 4, r = tid & 15;
            if (dones[(t0 + tp) * 256 + b0 + r]) atomicOr(&rowbits[r], 1u << tp);
        }
        __syncthreads();
        if (tid < 16) {
            unsigned m = rowbits[tid];
            sh_fd[tid] = m ? __builtin_ctz(m) : CHUNK;
        }
        __syncthreads();

        int maxfix = 0;
        unsigned rbr[4]; int fdr[4];
#pragma unroll
        for (int r = 0; r < 16; r++) maxfix = max(maxfix, sh_fd[r]);
#pragma unroll
        for (int r = 0; r < 4; r++) {
            rbr[r] = rowbits[rowg * 4 + r];
            fdr[r] = sh_fd[rowg * 4 + r];
        }
        // apply this chunk's step-0 reset to the carry
        if (rowbits[hrow] & 1u) {
#pragma unroll
            for (int cc = 0; cc < 8; cc++) hT[cur][hrow][hcol + cc] = 0;
        }
        __syncthreads();

        const size_t gb0 = ((size_t)(t0 * 16 + g) * 512 + tid) * 8;

        for (int tp = 0; tp < maxfix; tp++) {
            const int nxt = cur ^ 1;

            f32x4 acc0 = 0, acc1 = 0, acc2 = 0, acc3 = 0, acc4 = 0, acc5 = 0;
#pragma unroll
            for (int ks = 0; ks < 8; ks++) {
                short8 a = *(const short8*)&hT[cur][lc][ks * 32 + rowg * 8];
                acc0 = __builtin_amdgcn_mfma_f32_16x16x32_bf16(a, Bf[0][ks], acc0, 0, 0, 0);
                acc1 = __builtin_amdgcn_mfma_f32_16x16x32_bf16(a, Bf[1][ks], acc1, 0, 0, 0);
                acc2 = __builtin_amdgcn_mfma_f32_16x16x32_bf16(a, Bf[2][ks], acc2, 0, 0, 0);
                acc3 = __builtin_amdgcn_mfma_f32_16x16x32_bf16(a, Bf[3][ks], acc3, 0, 0, 0);
                acc4 = __builtin_amdgcn_mfma_f32_16x16x32_bf16(a, Bf[4][ks], acc4, 0, 0, 0);
                acc5 = __builtin_amdgcn_mfma_f32_16x16x32_bf16(a, Bf[5][ks], acc5, 0, 0, 0);
            }

            size_t gb = gb0 + (size_t)tp * gstep;
            short8 vir = *(const short8*)(gi + gb);
            short8 viz = *(const short8*)(gi + GIPL + gb);
            short8 vin = *(const short8*)(gi + 2 * GIPL + gb);

            unsigned short* yb = y + (size_t)((t0 + tp) * 256 + b0) * 256;
#pragma unroll
            for (int s = 0; s < 2; s++) {
                const int j = w * 32 + s * 16 + lc;
                f32x4 hrv = s ? acc1 : acc0;
                f32x4 hzv = s ? acc3 : acc2;
                f32x4 hnv = s ? acc5 : acc4;
                float bh = s ? bh1 : bh0;
#pragma unroll
                for (int r = 0; r < 4; r++) {
                    int row = rowg * 4 + r;
                    float ir  = bf2f((unsigned short)vir[r * 2 + s]);
                    float iz  = bf2f((unsigned short)viz[r * 2 + s]);
                    float inn = bf2f((unsigned short)vin[r * 2 + s]);
                    float ho  = bf2f(hT[cur][row][j]);
                    unsigned short hb = gru_cell(ir, iz, inn, ho, hrv[r], hzv[r], hnv[r], bh);
                    if (tp < fdr[r]) yb[row * 256 + j] = hb;   // only fix wrong prefix
                    unsigned short hw = hb;
                    if (tp + 1 < CHUNK && ((rbr[r] >> (tp + 1)) & 1u)) hw = 0;
                    hT[nxt][row][j] = hw;
                }
            }
            __syncthreads();
            cur = nxt;
        }

        // splice: rows that saw a done have correct speculative h_end
        if (sh_fd[hrow] < CHUNK) {
            *(short8*)&hT[cur][hrow][hcol] =
                *(const short8*)(hend + ((size_t)c * 256 + b0 + hrow) * 256 + hcol);
        }
        __syncthreads();
    }
}

// ---------------------------------------------------------------------------
extern "C" void kernel_launch(void* const* d_in, const int* in_sizes, int n_in,
                              void* d_out, int out_size, void* d_ws, size_t ws_size,
                              hipStream_t stream)
{
    const float* hidden = (const float*)d_in[0];
    const float* obs    = (const float*)d_in[1];
    const int*   dones  = (const int*)d_in[2];
    const int*   av1    = (const int*)d_in[3];
    const int*   av2    = (const int*)d_in[4];
    const int*   av3    = (const int*)d_in[5];
    const int*   av4    = (const int*)d_in[6];
    const float* W_emb  = (const float*)d_in[7];
    const float* b_emb  = (const float*)d_in[8];
    const float* Wi     = (const float*)d_in[9];
    const float* bi     = (const float*)d_in[10];
    const float* Wh     = (const float*)d_in[11];
    const float* bhn    = (const float*)d_in[12];
    const float* W_a    = (const float*)d_in[13];
    const float* b_a    = (const float*)d_in[14];
    const float* W_lc1  = (const float*)d_in[15];
    const float* b_lc1  = (const float*)d_in[16];
    const float* W_lc2  = (const float*)d_in[17];
    const float* b_lc2  = (const float*)d_in[18];
    const float* W_mc   = (const float*)d_in[19];
    const float* b_mc   = (const float*)d_in[20];
    const float* W_hint = (const float*)d_in[21];
    const float* b_hint = (const float*)d_in[22];
    const float* W_c1   = (const float*)d_in[23];
    const float* b_c1   = (const float*)d_in[24];
    const float* W_c2   = (const float*)d_in[25];
    const float* b_c2   = (const float*)d_in[26];

    char* ws = (char*)d_ws;
    unsigned short* WembF = (unsigned short*)(ws + 0);
    unsigned short* WiF   = (unsigned short*)(ws + 262144);
    unsigned short* WhF   = (unsigned short*)(ws + 655360);
    unsigned short* WacF  = (unsigned short*)(ws + 1048576);
    unsigned short* WlogF = (unsigned short*)(ws + 1310720);
    float*          blog  = (float*)(ws + 1392640);
    int*            fflag = (int*)(ws + 1393280);
    unsigned short* hend  = (unsigned short*)(ws + 1393664);
    unsigned short* gibuf = (unsigned short*)(ws + 135611392);
    unsigned short* ybuf  = (unsigned short*)(ws + 336937984);
    float* outp = (float*)d_out;

    k_prep<<<2721, 256, 0, stream>>>(W_emb, Wi, Wh, W_a, W_c1, W_lc1, W_lc2,
                                     W_mc, W_hint, b_lc1, b_lc2, b_mc, b_hint,
                                     WembF, WiF, WhF, WacF, WlogF, blog, fflag);
    k_fused_g12<<<2048, 512, 0, stream>>>(obs, WembF, b_emb, WiF, bi, gibuf);
    k_gru_main<<<256, 512, 0, stream>>>(gibuf, WhF, dones, hidden, bhn, ybuf, hend);
    k_gru_fix_par<<<240, 512, 0, stream>>>(gibuf, WhF, dones, bhn, hend, ybuf, fflag);
    k_gru_fix<<<16, 512, 0, stream>>>(gibuf, WhF, dones, bhn, hend, ybuf, fflag);
    k_head<<<2048, 512, 0, stream>>>(ybuf, WacF, b_a, b_c1, WlogF, blog,
                                     W_c2, b_c2, av1, av2, av3, av4, outp);
}

// Round 7
// 786.632 us; speedup vs baseline: 1.5921x; 1.0912x over previous
//
#include <hip/hip_runtime.h>
#include <stdint.h>

// ---------------------------------------------------------------------------
// ActorCriticRNN on MI355X.
//   prep:  weights -> bf16 FRAGMENT-LINEAR layouts (WembF/WiF/WacF/WlogF/WhF).
//   G12:   FUSED, 1m x 8n wave map: each wave owns ALL 64 rows x 2 n-frags,
//          so every B-frag is loaded exactly once per block (halves L2
//          broadcast traffic vs 2m x 4n). As double-buffered; eS in LDS;
//          phase 2 barrier-free; packed gate-plane output.
//   GRU:   chunk-parallel speculation (verified R2/R3 version).
//   HEAD:  fused G3+logits+critic+hidden, same 1m x 8n remap for the AC GEMM.
// ---------------------------------------------------------------------------

typedef short short8 __attribute__((ext_vector_type(8)));
typedef float f32x4  __attribute__((ext_vector_type(4)));

#define T_DIM 512
#define CHUNK 32
#define NCH   16
#define GIPL  ((size_t)33554432)   // gi gate-plane size in shorts (8192*512*8)

// output offsets (fp32 elements)
#define OUT_HID  ((size_t)0)
#define OUT_LC1  ((size_t)65536)
#define OUT_LC2  ((size_t)4259840)
#define OUT_MC   ((size_t)8454144)
#define OUT_HINT ((size_t)10551296)
#define OUT_CRIT ((size_t)18939904)

__device__ __forceinline__ unsigned short f2bf(float f) {
    unsigned u = __float_as_uint(f);
    u += 0x7fffu + ((u >> 16) & 1u);          // round-to-nearest-even
    return (unsigned short)(u >> 16);
}
__device__ __forceinline__ float bf2f(unsigned short h) {
    return __uint_as_float(((unsigned)h) << 16);
}

__device__ __forceinline__ unsigned short gru_cell(
    float ir, float iz, float inn, float ho,
    float hrv, float hzv, float hnv, float bh)
{
    float rg = 1.f / (1.f + __expf(-(ir + hrv)));
    float z  = 1.f / (1.f + __expf(-(iz + hzv)));
    float ex = __expf(2.f * (inn + rg * (hnv + bh)));
    float n  = 1.f - 2.f / (ex + 1.f);        // tanh, inf-safe
    return f2bf((1.f - z) * n + z * ho);
}

// ---------------------------------------------------------------------------
// prep: all weights to fragment-linear bf16 (verified R5).
// Fragment element convention (matches in-kernel MFMA usage everywhere):
//   lane L, elem jj ->  n = nbase + (L&15),  k = kbase + ((L>>4)<<3) + jj
// ---------------------------------------------------------------------------
__global__ __launch_bounds__(256, 4) void k_prep(
    const float* __restrict__ W_emb, const float* __restrict__ Wi,
    const float* __restrict__ Wh,    const float* __restrict__ W_a,
    const float* __restrict__ W_c1,  const float* __restrict__ W_lc1,
    const float* __restrict__ W_lc2, const float* __restrict__ W_mc,
    const float* __restrict__ W_hint,
    const float* __restrict__ b_lc1, const float* __restrict__ b_lc2,
    const float* __restrict__ b_mc,  const float* __restrict__ b_hint,
    unsigned short* __restrict__ WembF, unsigned short* __restrict__ WiF,
    unsigned short* __restrict__ WhF,   unsigned short* __restrict__ WacF,
    unsigned short* __restrict__ WlogF, float* __restrict__ blog,
    int* __restrict__ fixflag)
{
    int i = blockIdx.x * 256 + threadIdx.x;
    if (i < 131072) {                         // WembF: frag (q, j, kt32)
        int jj = i & 7, L = (i >> 3) & 63, kt32 = (i >> 9) & 15;
        int j = (i >> 13) & 3, q = (i >> 15) & 3;
        int n = q * 64 + j * 16 + (L & 15);
        int k = kt32 * 32 + ((L >> 4) << 3) + jj;
        WembF[i] = f2bf(W_emb[k * 256 + n]);
        return;
    }
    i -= 131072;
    if (i < 196608) {                         // WiF: frag (nc, q, j, kk32)
        int jj = i & 7, L = (i >> 3) & 63, kk32 = (i >> 9) & 7;
        int j = (i >> 12) & 3, q = (i >> 14) & 3, nc = i >> 16;
        int n = nc * 256 + q * 64 + j * 16 + (L & 15);
        int k = kk32 * 32 + ((L >> 4) << 3) + jj;
        WiF[i] = f2bf(Wi[k * 768 + n]);
        return;
    }
    i -= 196608;
    if (i < 196608) {                         // Wh fragment-linear (GRU, verified)
        int jj = i & 7, L = (i >> 3) & 63, ks = (i >> 9) & 7, rest = i >> 12;
        int w = rest / 6, i6 = rest % 6, rho = i6 >> 1, s = i6 & 1;
        int k   = ks * 32 + ((L >> 4) << 3) + jj;
        int col = rho * 256 + w * 32 + s * 16 + (L & 15);
        WhF[i] = f2bf(Wh[k * 768 + col]);
        return;
    }
    i -= 196608;
    if (i < 131072) {                         // WacF: frag (nc, q, j, kk32)
        int jj = i & 7, L = (i >> 3) & 63, kk32 = (i >> 9) & 7;
        int j = (i >> 12) & 3, q = (i >> 14) & 3, nc = (i >> 16) & 1;
        int n = nc * 256 + q * 64 + j * 16 + (L & 15);
        int k = kk32 * 32 + ((L >> 4) << 3) + jj;
        WacF[i] = f2bf(n < 256 ? W_a[k * 256 + n] : W_c1[k * 256 + (n - 256)]);
        return;
    }
    i -= 131072;
    if (i < 40960) {                          // WlogF: frag (j, kk32), N pad 160
        int jj = i & 7, L = (i >> 3) & 63, kk32 = (i >> 9) & 7;
        int j = i >> 12;                      // 0..9
        int n = j * 16 + (L & 15);
        int k = kk32 * 32 + ((L >> 4) << 3) + jj;
        float v;
        if      (n < 32)  v = W_lc1[k * 32 + n];
        else if (n < 64)  v = W_lc2[k * 32 + (n - 32)];
        else if (n < 80)  v = W_mc [k * 16 + (n - 64)];
        else if (n < 144) v = W_hint[k * 64 + (n - 80)];
        else              v = 0.f;
        WlogF[i] = f2bf(v);
        return;
    }
    i -= 40960;
    if (i < 160) {
        float v;
        if      (i < 32)  v = b_lc1[i];
        else if (i < 64)  v = b_lc2[i - 32];
        else if (i < 80)  v = b_mc [i - 64];
        else if (i < 144) v = b_hint[i - 80];
        else              v = 0.f;
        blog[i] = v;
        return;
    }
    i -= 160;
    if (i == 0) *fixflag = 0;
}

// ---------------------------------------------------------------------------
// FUSED G1+G2. 2048 blocks x 64 rows, 512 threads = 8 waves, 1m x 8n map:
// wave w owns ALL 64 rows (4 m-frags) x 2 n-frags (cols w*32..w*32+31).
// Every B-frag loaded once per block (minimum L2 broadcast traffic).
//   phase 1: As double-buffered (1 barrier/kt), B direct from WembF.
//   phase 2: 3 gate chunks, a from eS, b direct from WiF. ZERO barriers.
// ---------------------------------------------------------------------------
__global__ __launch_bounds__(512, 3) void k_fused_g12(
    const float* __restrict__ obs, const unsigned short* __restrict__ WembF,
    const float* __restrict__ b_emb, const unsigned short* __restrict__ WiF,
    const float* __restrict__ bi, unsigned short* __restrict__ out)
{
    __shared__ unsigned short As[2][64][72];
    __shared__ unsigned short eS[64][264];
    const int tid = threadIdx.x, w = tid >> 6, L = tid & 63;
    const int m0 = blockIdx.x * 64;
    const int lc = L & 15, lq8 = (L >> 4) * 8, lr = (L >> 4) * 4;
    const int sra = tid >> 3, sha = (tid & 7) * 8;   // As staging: 8 thr/row

    const float* Ag = obs + (size_t)(m0 + sra) * 512 + sha;

    auto stage_a = [&](int kt, int p) {
        f32x4 v0 = *(const f32x4*)(Ag + kt);
        f32x4 v1 = *(const f32x4*)(Ag + kt + 4);
        short8 pk;
        pk[0] = (short)f2bf(v0[0]); pk[1] = (short)f2bf(v0[1]);
        pk[2] = (short)f2bf(v0[2]); pk[3] = (short)f2bf(v0[3]);
        pk[4] = (short)f2bf(v1[0]); pk[5] = (short)f2bf(v1[1]);
        pk[6] = (short)f2bf(v1[2]); pk[7] = (short)f2bf(v1[3]);
        *(short8*)&As[p][sra][sha] = pk;
    };

    f32x4 acc[4][2];
#pragma unroll
    for (int i = 0; i < 4; i++)
#pragma unroll
        for (int jn = 0; jn < 2; jn++) acc[i][jn] = 0;

    // ---- phase 1: acc = obs @ WembF ----
    stage_a(0, 0);
    __syncthreads();
    int p = 0;
    for (int kt = 0; kt < 512; kt += 64) {
        if (kt + 64 < 512) stage_a(kt + 64, p ^ 1);
#pragma unroll
        for (int ks = 0; ks < 2; ks++) {
            const int kt32 = (kt >> 5) + ks;
            short8 a[4], b[2];
#pragma unroll
            for (int i = 0; i < 4; i++)
                a[i] = *(const short8*)&As[p][i * 16 + lc][ks * 32 + lq8];
#pragma unroll
            for (int jn = 0; jn < 2; jn++)
                b[jn] = *(const short8*)(WembF +
                        ((((size_t)(w * 2 + jn) * 16 + kt32) * 64 + L) * 8));
#pragma unroll
            for (int i = 0; i < 4; i++)
#pragma unroll
                for (int jn = 0; jn < 2; jn++)
                    acc[i][jn] = __builtin_amdgcn_mfma_f32_16x16x32_bf16(a[i], b[jn], acc[i][jn], 0, 0, 0);
        }
        __syncthreads();
        p ^= 1;
    }
    // epilogue phase 1: relu -> bf16 -> eS
#pragma unroll
    for (int i = 0; i < 4; i++)
#pragma unroll
        for (int jn = 0; jn < 2; jn++) {
            int col = (w * 2 + jn) * 16 + lc;
            float bv = b_emb[col];
#pragma unroll
            for (int rg = 0; rg < 4; rg++) {
                int row = i * 16 + lr + rg;
                eS[row][col] = f2bf(fmaxf(acc[i][jn][rg] + bv, 0.f));
            }
        }
    __syncthreads();

    // ---- phase 2: gi = eS @ WiF + bi, 3 gate chunks, no barriers ----
    for (int nc = 0; nc < 3; nc++) {
        f32x4 acc2[4][2];
#pragma unroll
        for (int i = 0; i < 4; i++)
#pragma unroll
            for (int jn = 0; jn < 2; jn++) acc2[i][jn] = 0;

#pragma unroll 2
        for (int kk32 = 0; kk32 < 8; kk32++) {
            short8 a[4], b[2];
#pragma unroll
            for (int i = 0; i < 4; i++)
                a[i] = *(const short8*)&eS[i * 16 + lc][kk32 * 32 + lq8];
#pragma unroll
            for (int jn = 0; jn < 2; jn++)
                b[jn] = *(const short8*)(WiF +
                        ((((size_t)(nc * 16 + w * 2 + jn) * 8 + kk32) * 64 + L) * 8));
#pragma unroll
            for (int i = 0; i < 4; i++)
#pragma unroll
                for (int jn = 0; jn < 2; jn++)
                    acc2[i][jn] = __builtin_amdgcn_mfma_f32_16x16x32_bf16(a[i], b[jn], acc2[i][jn], 0, 0, 0);
        }
        // packed epilogue (same verified (row,col)->(dst,elem) function)
        const int colb = nc * 256 + w * 32;
        const int gate = colb >> 8;              // == nc
        const int w2   = (colb & 255) >> 5;      // == w
#pragma unroll
        for (int i = 0; i < 4; i++) {
            const int row0  = m0 + i * 16 + lr;
            const int t     = row0 >> 8;
            const int g     = (row0 >> 4) & 15;
            const int rowg2 = (row0 >> 2) & 3;
            short8 pk;
#pragma unroll
            for (int rg = 0; rg < 4; rg++)
#pragma unroll
                for (int s = 0; s < 2; s++) {
                    int col = colb + s * 16 + lc;
                    float v = acc2[i][s][rg] + bi[col];
                    pk[rg * 2 + s] = (short)f2bf(v);
                }
            size_t dst = (size_t)gate * GIPL +
                         (((size_t)(t * 16 + g) * 512) + (size_t)w2 * 64 +
                          (size_t)rowg2 * 16 + lc) * 8;
            *(short8*)(out + dst) = pk;
        }
    }
}

// ---------------------------------------------------------------------------
// HEAD: fused G3 + logits + critic + hidden. 2048 blocks x 64 rows, 512 thr.
// AC GEMM uses 1m x 8n map: wave w covers fc = w*4..w*4+3 (fc<16 -> A,
// fc>=16 -> C), all 64 rows; every B-frag loaded once per block.
// ---------------------------------------------------------------------------
__global__ __launch_bounds__(512, 2) void k_head(
    const unsigned short* __restrict__ y, const unsigned short* __restrict__ WacF,
    const float* __restrict__ b_a, const float* __restrict__ b_c1,
    const unsigned short* __restrict__ WlogF, const float* __restrict__ blog,
    const float* __restrict__ W_c2, const float* __restrict__ b_c2,
    const int* __restrict__ av1, const int* __restrict__ av2,
    const int* __restrict__ av3, const int* __restrict__ av4,
    float* __restrict__ outp)
{
    __shared__ unsigned short yS[64][264];   // reused as cS after the GEMM
    __shared__ unsigned short aS[64][264];
    const int tid = threadIdx.x, w = tid >> 6, L = tid & 63;
    const int m0 = blockIdx.x * 64;
    const int lc = L & 15, lq8 = (L >> 4) * 8, lr = (L >> 4) * 4;

    // stage y tile once: 32 shorts/thread, coalesced
    {
        int r = tid >> 3, cb = (tid & 7) * 32;
        const unsigned short* yg = y + (size_t)(m0 + r) * 256 + cb;
#pragma unroll
        for (int c = 0; c < 32; c += 8)
            *(short8*)&yS[r][cb + c] = *(const short8*)(yg + c);
    }
    __syncthreads();

    // hidden output: rows of t = 511 live in blocks with m0 >= 130816
    if (m0 >= 130816) {
        int r = tid >> 3, cb = (tid & 7) * 32;
        int b = (m0 - 130816) + r;
#pragma unroll
        for (int c = 0; c < 32; c++)
            outp[OUT_HID + (size_t)b * 256 + cb + c] = bf2f(yS[r][cb + c]);
    }

    // ---- [a|c] GEMM: 1m x 8n; acc[i m-frag][u fc-local] ----
    f32x4 acc[4][4];
#pragma unroll
    for (int i = 0; i < 4; i++)
#pragma unroll
        for (int u = 0; u < 4; u++) acc[i][u] = 0;

#pragma unroll 2
    for (int kk32 = 0; kk32 < 8; kk32++) {
        short8 a[4], b[4];
#pragma unroll
        for (int i = 0; i < 4; i++)
            a[i] = *(const short8*)&yS[i * 16 + lc][kk32 * 32 + lq8];
#pragma unroll
        for (int u = 0; u < 4; u++)
            b[u] = *(const short8*)(WacF +
                    ((((size_t)(w * 4 + u) * 8 + kk32) * 64 + L) * 8));
#pragma unroll
        for (int i = 0; i < 4; i++)
#pragma unroll
            for (int u = 0; u < 4; u++)
                acc[i][u] = __builtin_amdgcn_mfma_f32_16x16x32_bf16(a[i], b[u], acc[i][u], 0, 0, 0);
    }
    __syncthreads();   // all yS reads done; safe to overwrite

    // write a -> aS, c -> yS (cS); bf16 rounding identical to old path
#pragma unroll
    for (int i = 0; i < 4; i++)
#pragma unroll
        for (int u = 0; u < 4; u++) {
            int fc = w * 4 + u;
#pragma unroll
            for (int rg = 0; rg < 4; rg++) {
                int row = i * 16 + lr + rg;
                if (fc < 16) {
                    int col = fc * 16 + lc;
                    aS[row][col] = f2bf(fmaxf(acc[i][u][rg] + b_a[col], 0.f));
                } else {
                    int col = (fc - 16) * 16 + lc;
                    yS[row][col] = f2bf(fmaxf(acc[i][u][rg] + b_c1[col], 0.f));
                }
            }
        }
    __syncthreads();

    // ---- logits: A from aS, B from WlogF; wave: mf = w>>1, jh = (w&1)*5 ----
    {
        const int mf = w >> 1, jh = (w & 1) * 5;
        f32x4 accL[5];
#pragma unroll
        for (int j5 = 0; j5 < 5; j5++) accL[j5] = 0;

#pragma unroll 2
        for (int kk32 = 0; kk32 < 8; kk32++) {
            short8 a = *(const short8*)&aS[mf * 16 + lc][kk32 * 32 + lq8];
#pragma unroll
            for (int j5 = 0; j5 < 5; j5++) {
                short8 b = *(const short8*)(WlogF +
                        ((((size_t)(jh + j5) * 8 + kk32) * 64 + L) * 8));
                accL[j5] = __builtin_amdgcn_mfma_f32_16x16x32_bf16(a, b, accL[j5], 0, 0, 0);
            }
        }
#pragma unroll
        for (int j5 = 0; j5 < 5; j5++) {
            int col = (jh + j5) * 16 + lc;
            if (col >= 144) continue;
            int gbase, adim; const int* av; size_t obase;
            if      (col < 32) { gbase = 0;  adim = 32; av = av1; obase = OUT_LC1; }
            else if (col < 64) { gbase = 32; adim = 32; av = av2; obase = OUT_LC2; }
            else if (col < 80) { gbase = 64; adim = 16; av = av3; obase = OUT_MC;  }
            else               { gbase = 80; adim = 64; av = av4; obase = OUT_HINT;}
            int cof = col - gbase;
            float bv = blog[col];
#pragma unroll
            for (int rg = 0; rg < 4; rg++) {
                int R = m0 + mf * 16 + lr + rg;
                float v = accL[j5][rg] + bv;
                int a_ = av[(size_t)R * adim + cof];
                v -= (1.f - (float)a_) * 1e10f;
                outp[obase + (size_t)R * adim + cof] = v;
            }
        }
    }

    // ---- critic: per-row dot of cS (=yS) with W_c2, 8 rows per wave ----
    {
        f32x4 wv = *(const f32x4*)(W_c2 + L * 4);
        float bb = b_c2[0];
#pragma unroll
        for (int rr = 0; rr < 8; rr++) {
            int row = w * 8 + rr;
            const unsigned short* pc = &yS[row][L * 4];
            float s = bf2f(pc[0]) * wv[0] + bf2f(pc[1]) * wv[1] +
                      bf2f(pc[2]) * wv[2] + bf2f(pc[3]) * wv[3];
#pragma unroll
            for (int o = 32; o > 0; o >>= 1) s += __shfl_down(s, o);
            if (L == 0) outp[OUT_CRIT + m0 + row] = s + bb;
        }
    }
}

// ---------------------------------------------------------------------------
// GRU main pass (verified R2/R3 version)
// ---------------------------------------------------------------------------
__global__ __launch_bounds__(512, 1) void k_gru_main(
    const unsigned short* __restrict__ gi, const unsigned short* __restrict__ WhF,
    const int* __restrict__ dones, const float* __restrict__ h0,
    const float* __restrict__ bhn, unsigned short* __restrict__ y,
    unsigned short* __restrict__ hend)
{
    __shared__ unsigned short hT[2][16][264];
    __shared__ unsigned short yS[2][16][256];
    __shared__ unsigned int rowbits[16];      // bit t' of dones for each row
    const int tid = threadIdx.x, w = tid >> 6, L = tid & 63;
    const int g = blockIdx.x & 15, c = blockIdx.x >> 4;
    const int b0 = g * 16, t0 = c * CHUNK;
    const int rowg = L >> 4, lc = L & 15;

    short8 Bf[6][8];
#pragma unroll
    for (int i6 = 0; i6 < 6; i6++)
#pragma unroll
        for (int ks = 0; ks < 8; ks++)
            Bf[i6][ks] = *(const short8*)(WhF + ((((size_t)w * 6 + i6) * 8 + ks) * 64 + L) * 8);

    const float bh0 = bhn[w * 32 + lc], bh1 = bhn[w * 32 + 16 + lc];

    // build dones bitmask for this chunk
    if (tid < 16) rowbits[tid] = 0;
    __syncthreads();
    {
        int tp = tid >> 4, r = tid & 15;
        if (dones[(t0 + tp) * 256 + b0 + r]) atomicOr(&rowbits[r], 1u << tp);
    }
    __syncthreads();

    unsigned rbr[4];
#pragma unroll
    for (int r = 0; r < 4; r++) rbr[r] = rowbits[rowg * 4 + r];

    // init h: c==0 -> h0 with done[0] reset; c>0 -> speculative 0
    {
        int hrow = tid >> 5, hcol = (tid & 31) * 8;
        bool rz = (rowbits[hrow] & 1u) != 0;
#pragma unroll
        for (int cc = 0; cc < 8; cc++) {
            unsigned short v = 0;
            if (c == 0 && !rz) v = f2bf(h0[(b0 + hrow) * 256 + hcol + cc]);
            hT[0][hrow][hcol + cc] = v;
        }
    }
    __syncthreads();

    // gi packed base for this thread: ((t*16+g)*512 + tid)*8, t = t0+tp
    const size_t gstep = (size_t)16 * 512 * 8;
    size_t gb = ((size_t)(t0 * 16 + g) * 512 + tid) * 8;
    short8 vir = *(const short8*)(gi + gb);
    short8 viz = *(const short8*)(gi + GIPL + gb);
    short8 vin = *(const short8*)(gi + 2 * GIPL + gb);

#pragma unroll 2
    for (int tp = 0; tp < CHUNK; tp++) {
        const int cur = tp & 1, nxt = cur ^ 1;
        const int t = t0 + tp;

        // prefetch next step's gi (independent of h)
        short8 nir, niz, nin;
        if (tp + 1 < CHUNK) {
            size_t gn = gb + (size_t)(tp + 1) * gstep;
            nir = *(const short8*)(gi + gn);
            niz = *(const short8*)(gi + GIPL + gn);
            nin = *(const short8*)(gi + 2 * GIPL + gn);
        }

        f32x4 acc0 = 0, acc1 = 0, acc2 = 0, acc3 = 0, acc4 = 0, acc5 = 0;
#pragma unroll
        for (int ks = 0; ks < 8; ks++) {
            short8 a = *(const short8*)&hT[cur][lc][ks * 32 + rowg * 8];
            acc0 = __builtin_amdgcn_mfma_f32_16x16x32_bf16(a, Bf[0][ks], acc0, 0, 0, 0);
            acc1 = __builtin_amdgcn_mfma_f32_16x16x32_bf16(a, Bf[1][ks], acc1, 0, 0, 0);
            acc2 = __builtin_amdgcn_mfma_f32_16x16x32_bf16(a, Bf[2][ks], acc2, 0, 0, 0);
            acc3 = __builtin_amdgcn_mfma_f32_16x16x32_bf16(a, Bf[3][ks], acc3, 0, 0, 0);
            acc4 = __builtin_amdgcn_mfma_f32_16x16x32_bf16(a, Bf[4][ks], acc4, 0, 0, 0);
            acc5 = __builtin_amdgcn_mfma_f32_16x16x32_bf16(a, Bf[5][ks], acc5, 0, 0, 0);
        }

#pragma unroll
        for (int s = 0; s < 2; s++) {
            const int j = w * 32 + s * 16 + lc;
            f32x4 hrv = s ? acc1 : acc0;
            f32x4 hzv = s ? acc3 : acc2;
            f32x4 hnv = s ? acc5 : acc4;
            float bh = s ? bh1 : bh0;
#pragma unroll
            for (int r = 0; r < 4; r++) {
                int row = rowg * 4 + r;
                float ir  = bf2f((unsigned short)vir[r * 2 + s]);
                float iz  = bf2f((unsigned short)viz[r * 2 + s]);
                float inn = bf2f((unsigned short)vin[r * 2 + s]);
                float ho  = bf2f(hT[cur][row][j]);
                unsigned short hb = gru_cell(ir, iz, inn, ho, hrv[r], hzv[r], hnv[r], bh);
                yS[cur][row][j] = hb;
                unsigned short hw = hb;
                if (tp + 1 < CHUNK && ((rbr[r] >> (tp + 1)) & 1u)) hw = 0;
                hT[nxt][row][j] = hw;
            }
        }
        __syncthreads();

        // coalesced y store (one 16B full-line write per thread)
        {
            int yrow = tid >> 5, ycol = (tid & 31) * 8;
            short8 yv = *(const short8*)&yS[cur][yrow][ycol];
            *(short8*)(y + ((size_t)t * 256 + b0 + yrow) * 256 + ycol) = yv;
            if (tp == CHUNK - 1)
                *(short8*)(hend + ((size_t)c * 256 + b0 + yrow) * 256 + ycol) = yv;
        }

        vir = nir; viz = niz; vin = nin;
    }
}

// ---------------------------------------------------------------------------
// PARALLEL GRU fixup (verified): 240 WGs = (chunk 1..15) x (16 tiles).
// ---------------------------------------------------------------------------
__global__ __launch_bounds__(512, 1) void k_gru_fix_par(
    const unsigned short* __restrict__ gi, const unsigned short* __restrict__ WhF,
    const int* __restrict__ dones, const float* __restrict__ bhn,
    const unsigned short* __restrict__ hend, unsigned short* __restrict__ y,
    int* __restrict__ flag)
{
    __shared__ unsigned short hT[2][16][264];
    __shared__ unsigned int rowbits[16], prevbits[16];
    __shared__ int sh_fd[16];
    const int tid = threadIdx.x, w = tid >> 6, L = tid & 63;
    const int g = blockIdx.x & 15, c = (blockIdx.x >> 4) + 1;
    const int b0 = g * 16, t0 = c * CHUNK;
    const int rowg = L >> 4, lc = L & 15;
    const int hrow = tid >> 5, hcol = (tid & 31) * 8;

    short8 Bf[6][8];
#pragma unroll
    for (int i6 = 0; i6 < 6; i6++)
#pragma unroll
        for (int ks = 0; ks < 8; ks++)
            Bf[i6][ks] = *(const short8*)(WhF + ((((size_t)w * 6 + i6) * 8 + ks) * 64 + L) * 8);

    const float bh0 = bhn[w * 32 + lc], bh1 = bhn[w * 32 + 16 + lc];

    if (tid < 16) { rowbits[tid] = 0; prevbits[tid] = 0; }
    __syncthreads();
    {
        int tp = tid >> 4, r = tid & 15;
        if (dones[(t0 + tp) * 256 + b0 + r])         atomicOr(&rowbits[r],  1u << tp);
        if (dones[(t0 - CHUNK + tp) * 256 + b0 + r]) atomicOr(&prevbits[r], 1u << tp);
    }
    __syncthreads();
    if (tid < 16) {
        unsigned m = rowbits[tid];
        sh_fd[tid] = m ? __builtin_ctz(m) : CHUNK;
        if (prevbits[tid] == 0) atomicOr(flag, 1);   // carry-in untrusted
    }
    __syncthreads();

    int maxfix = 0;
    unsigned rbr[4]; int fdr[4];
#pragma unroll
    for (int r = 0; r < 16; r++) maxfix = max(maxfix, sh_fd[r]);
    if (maxfix == 0) return;                          // all rows reset at step 0
#pragma unroll
    for (int r = 0; r < 4; r++) {
        rbr[r] = rowbits[rowg * 4 + r];
        fdr[r] = sh_fd[rowg * 4 + r];
    }

    // carry-in: speculative end of chunk c-1, with chunk-c step-0 reset
    {
        short8 hv = *(const short8*)(hend + ((size_t)(c - 1) * 256 + b0 + hrow) * 256 + hcol);
        if (rowbits[hrow] & 1u) { short8 z = {0,0,0,0,0,0,0,0}; hv = z; }
        *(short8*)&hT[0][hrow][hcol] = hv;
    }
    __syncthreads();

    const size_t gstep = (size_t)16 * 512 * 8;
    const size_t gb0 = ((size_t)(t0 * 16 + g) * 512 + tid) * 8;

    int cur = 0;
    for (int tp = 0; tp < maxfix; tp++) {
        const int nxt = cur ^ 1;

        f32x4 acc0 = 0, acc1 = 0, acc2 = 0, acc3 = 0, acc4 = 0, acc5 = 0;
#pragma unroll
        for (int ks = 0; ks < 8; ks++) {
            short8 a = *(const short8*)&hT[cur][lc][ks * 32 + rowg * 8];
            acc0 = __builtin_amdgcn_mfma_f32_16x16x32_bf16(a, Bf[0][ks], acc0, 0, 0, 0);
            acc1 = __builtin_amdgcn_mfma_f32_16x16x32_bf16(a, Bf[1][ks], acc1, 0, 0, 0);
            acc2 = __builtin_amdgcn_mfma_f32_16x16x32_bf16(a, Bf[2][ks], acc2, 0, 0, 0);
            acc3 = __builtin_amdgcn_mfma_f32_16x16x32_bf16(a, Bf[3][ks], acc3, 0, 0, 0);
            acc4 = __builtin_amdgcn_mfma_f32_16x16x32_bf16(a, Bf[4][ks], acc4, 0, 0, 0);
            acc5 = __builtin_amdgcn_mfma_f32_16x16x32_bf16(a, Bf[5][ks], acc5, 0, 0, 0);
        }

        size_t gb = gb0 + (size_t)tp * gstep;
        short8 vir = *(const short8*)(gi + gb);
        short8 viz = *(const short8*)(gi + GIPL + gb);
        short8 vin = *(const short8*)(gi + 2 * GIPL + gb);

        unsigned short* yb = y + (size_t)((t0 + tp) * 256 + b0) * 256;
#pragma unroll
        for (int s = 0; s < 2; s++) {
            const int j = w * 32 + s * 16 + lc;
            f32x4 hrv = s ? acc1 : acc0;
            f32x4 hzv = s ? acc3 : acc2;
            f32x4 hnv = s ? acc5 : acc4;
            float bh = s ? bh1 : bh0;
#pragma unroll
            for (int r = 0; r < 4; r++) {
                int row = rowg * 4 + r;
                float ir  = bf2f((unsigned short)vir[r * 2 + s]);
                float iz  = bf2f((unsigned short)viz[r * 2 + s]);
                float inn = bf2f((unsigned short)vin[r * 2 + s]);
                float ho  = bf2f(hT[cur][row][j]);
                unsigned short hb = gru_cell(ir, iz, inn, ho, hrv[r], hzv[r], hnv[r], bh);
                if (tp < fdr[r]) yb[row * 256 + j] = hb;   // only fix wrong prefix
                unsigned short hw = hb;
                if (tp + 1 < CHUNK && ((rbr[r] >> (tp + 1)) & 1u)) hw = 0;
                hT[nxt][row][j] = hw;
            }
        }
        __syncthreads();
        cur = nxt;
    }
}

// ---------------------------------------------------------------------------
// GRU fixup FALLBACK (sequential over chunks): only runs if flag was set.
// ---------------------------------------------------------------------------
__global__ __launch_bounds__(512, 1) void k_gru_fix(
    const unsigned short* __restrict__ gi, const unsigned short* __restrict__ WhF,
    const int* __restrict__ dones, const float* __restrict__ bhn,
    const unsigned short* __restrict__ hend, unsigned short* __restrict__ y,
    const int* __restrict__ flag)
{
    if (*flag == 0) return;                   // uniform: common case, exit fast

    __shared__ unsigned short hT[2][16][264];
    __shared__ unsigned int rowbits[16];
    __shared__ int sh_fd[16];
    const int tid = threadIdx.x, w = tid >> 6, L = tid & 63;
    const int b0 = blockIdx.x * 16, g = blockIdx.x;
    const int rowg = L >> 4, lc = L & 15;
    const int hrow = tid >> 5, hcol = (tid & 31) * 8;

    short8 Bf[6][8];
#pragma unroll
    for (int i6 = 0; i6 < 6; i6++)
#pragma unroll
        for (int ks = 0; ks < 8; ks++)
            Bf[i6][ks] = *(const short8*)(WhF + ((((size_t)w * 6 + i6) * 8 + ks) * 64 + L) * 8);

    const float bh0 = bhn[w * 32 + lc], bh1 = bhn[w * 32 + 16 + lc];

    // carry = corrected end of chunk 0 (chunk 0 speculation used true h0)
    *(short8*)&hT[0][hrow][hcol] =
        *(const short8*)(hend + (size_t)(b0 + hrow) * 256 + hcol);
    int cur = 0;

    const size_t gstep = (size_t)16 * 512 * 8;

    for (int c = 1; c < NCH; c++) {
        const int t0 = c * CHUNK;
        if (tid < 16) rowbits[tid] = 0;
        __syncthreads();
        {
            int tp = tid >> 4, r = tid & 15;
            if (dones[(t0 + tp) * 256 + b0 + r]) atomicOr(&rowbits[r], 1u << tp);
        }
        __syncthreads();
        if (tid < 16) {
            unsigned m = rowbits[tid];
            sh_fd[tid] = m ? __builtin_ctz(m) : CHUNK;
        }
        __syncthreads();

        int maxfix = 0;
        unsigned rbr[4]; int fdr[4];
#pragma unroll
        for (int r = 0; r < 16; r++) maxfix = max(maxfix, sh_fd[r]);
#pragma unroll
        for (int r = 0; r < 4; r++) {
            rbr[r] = rowbits[rowg * 4 + r];
            fdr[r] = sh_fd[rowg * 4 + r];
        }
        // apply this chunk's step-0 reset to the carry
        if (rowbits[hrow] & 1u) {
#pragma unroll
            for (int cc = 0; cc < 8; cc++) hT[cur][hrow][hcol + cc] = 0;
        }
        __syncthreads();

        const size_t gb0 = ((size_t)(t0 * 16 + g) * 512 + tid) * 8;

        for (int tp = 0; tp < maxfix; tp++) {
            const int nxt = cur ^ 1;

            f32x4 acc0 = 0, acc1 = 0, acc2 = 0, acc3 = 0, acc4 = 0, acc5 = 0;
#pragma unroll
            for (int ks = 0; ks < 8; ks++) {
                short8 a = *(const short8*)&hT[cur][lc][ks * 32 + rowg * 8];
                acc0 = __builtin_amdgcn_mfma_f32_16x16x32_bf16(a, Bf[0][ks], acc0, 0, 0, 0);
                acc1 = __builtin_amdgcn_mfma_f32_16x16x32_bf16(a, Bf[1][ks], acc1, 0, 0, 0);
                acc2 = __builtin_amdgcn_mfma_f32_16x16x32_bf16(a, Bf[2][ks], acc2, 0, 0, 0);
                acc3 = __builtin_amdgcn_mfma_f32_16x16x32_bf16(a, Bf[3][ks], acc3, 0, 0, 0);
                acc4 = __builtin_amdgcn_mfma_f32_16x16x32_bf16(a, Bf[4][ks], acc4, 0, 0, 0);
                acc5 = __builtin_amdgcn_mfma_f32_16x16x32_bf16(a, Bf[5][ks], acc5, 0, 0, 0);
            }

            size_t gb = gb0 + (size_t)tp * gstep;
            short8 vir = *(const short8*)(gi + gb);
            short8 viz = *(const short8*)(gi + GIPL + gb);
            short8 vin = *(const short8*)(gi + 2 * GIPL + gb);

            unsigned short* yb = y + (size_t)((t0 + tp) * 256 + b0) * 256;
#pragma unroll
            for (int s = 0; s < 2; s++) {
                const int j = w * 32 + s * 16 + lc;
                f32x4 hrv = s ? acc1 : acc0;
                f32x4 hzv = s ? acc3 : acc2;
                f32x4 hnv = s ? acc5 : acc4;
                float bh = s ? bh1 : bh0;
#pragma unroll
                for (int r = 0; r < 4; r++) {
                    int row = rowg * 4 + r;
                    float ir  = bf2f((unsigned short)vir[r * 2 + s]);
                    float iz  = bf2f((unsigned short)viz[r * 2 + s]);
                    float inn = bf2f((unsigned short)vin[r * 2 + s]);
                    float ho  = bf2f(hT[cur][row][j]);
                    unsigned short hb = gru_cell(ir, iz, inn, ho, hrv[r], hzv[r], hnv[r], bh);
                    if (tp < fdr[r]) yb[row * 256 + j] = hb;   // only fix wrong prefix
                    unsigned short hw = hb;
                    if (tp + 1 < CHUNK && ((rbr[r] >> (tp + 1)) & 1u)) hw = 0;
                    hT[nxt][row][j] = hw;
                }
            }
            __syncthreads();
            cur = nxt;
        }

        // splice: rows that saw a done have correct speculative h_end
        if (sh_fd[hrow] < CHUNK) {
            *(short8*)&hT[cur][hrow][hcol] =
                *(const short8*)(hend + ((size_t)c * 256 + b0 + hrow) * 256 + hcol);
        }
        __syncthreads();
    }
}

// ---------------------------------------------------------------------------
extern "C" void kernel_launch(void* const* d_in, const int* in_sizes, int n_in,
                              void* d_out, int out_size, void* d_ws, size_t ws_size,
                              hipStream_t stream)
{
    const float* hidden = (const float*)d_in[0];
    const float* obs    = (const float*)d_in[1];
    const int*   dones  = (const int*)d_in[2];
    const int*   av1    = (const int*)d_in[3];
    const int*   av2    = (const int*)d_in[4];
    const int*   av3    = (const int*)d_in[5];
    const int*   av4    = (const int*)d_in[6];
    const float* W_emb  = (const float*)d_in[7];
    const float* b_emb  = (const float*)d_in[8];
    const float* Wi     = (const float*)d_in[9];
    const float* bi     = (const float*)d_in[10];
    const float* Wh     = (const float*)d_in[11];
    const float* bhn    = (const float*)d_in[12];
    const float* W_a    = (const float*)d_in[13];
    const float* b_a    = (const float*)d_in[14];
    const float* W_lc1  = (const float*)d_in[15];
    const float* b_lc1  = (const float*)d_in[16];
    const float* W_lc2  = (const float*)d_in[17];
    const float* b_lc2  = (const float*)d_in[18];
    const float* W_mc   = (const float*)d_in[19];
    const float* b_mc   = (const float*)d_in[20];
    const float* W_hint = (const float*)d_in[21];
    const float* b_hint = (const float*)d_in[22];
    const float* W_c1   = (const float*)d_in[23];
    const float* b_c1   = (const float*)d_in[24];
    const float* W_c2   = (const float*)d_in[25];
    const float* b_c2   = (const float*)d_in[26];

    char* ws = (char*)d_ws;
    unsigned short* WembF = (unsigned short*)(ws + 0);
    unsigned short* WiF   = (unsigned short*)(ws + 262144);
    unsigned short* WhF   = (unsigned short*)(ws + 655360);
    unsigned short* WacF  = (unsigned short*)(ws + 1048576);
    unsigned short* WlogF = (unsigned short*)(ws + 1310720);
    float*          blog  = (float*)(ws + 1392640);
    int*            fflag = (int*)(ws + 1393280);
    unsigned short* hend  = (unsigned short*)(ws + 1393664);
    unsigned short* gibuf = (unsigned short*)(ws + 135611392);
    unsigned short* ybuf  = (unsigned short*)(ws + 336937984);
    float* outp = (float*)d_out;

    k_prep<<<2721, 256, 0, stream>>>(W_emb, Wi, Wh, W_a, W_c1, W_lc1, W_lc2,
                                     W_mc, W_hint, b_lc1, b_lc2, b_mc, b_hint,
                                     WembF, WiF, WhF, WacF, WlogF, blog, fflag);
    k_fused_g12<<<2048, 512, 0, stream>>>(obs, WembF, b_emb, WiF, bi, gibuf);
    k_gru_main<<<256, 512, 0, stream>>>(gibuf, WhF, dones, hidden, bhn, ybuf, hend);
    k_gru_fix_par<<<240, 512, 0, stream>>>(gibuf, WhF, dones, bhn, hend, ybuf, fflag);
    k_gru_fix<<<16, 512, 0, stream>>>(gibuf, WhF, dones, bhn, hend, ybuf, fflag);
    k_head<<<2048, 512, 0, stream>>>(ybuf, WacF, b_a, b_c1, WlogF, blog,
                                     W_c2, b_c2, av1, av2, av3, av4, outp);
}